// Round 3
// baseline (867.754 us; speedup 1.0000x reference)
//
#include <hip/hip_runtime.h>
#include <cstddef>

#define NPIX 65536
#define PI_F 3.14159265358979323846f

__device__ __forceinline__ void cacc(float2& acc, float2 a, float2 b) {
  acc.x = fmaf(a.x, b.x, fmaf(-a.y, b.y, acc.x));
  acc.y = fmaf(a.x, b.y, fmaf(a.y, b.x, acc.y));
}

// ---------------- 256-point radix-2 DIT FFT in LDS (one wave per line) -----
__device__ __forceinline__ void fft256(float* re, float* im, const float* twr,
                                       const float* twi, int lane) {
  #pragma unroll
  for (int s = 0; s < 8; ++s) {
    __syncthreads();
    const int half = 1 << s;
    #pragma unroll
    for (int r = 0; r < 2; ++r) {
      int m  = lane + 64*r;
      int t  = m & (half - 1);
      int g  = m >> s;
      int i0 = (g << (s+1)) + t;
      int i1 = i0 + half;
      int ti = t << (7 - s);
      float wr = twr[ti], wi = twi[ti];
      float br = re[i1], bi = im[i1];
      float vr = br*wr - bi*wi;
      float vi = br*wi + bi*wr;
      float ar = re[i0], ai = im[i0];
      re[i0] = ar + vr; im[i0] = ai + vi;
      re[i1] = ar - vr; im[i1] = ai - vi;
    }
  }
  __syncthreads();
}

// ---------------- setup: A1, A2T, E1, E2 ------------------------------------
__global__ __launch_bounds__(256) void k_setup(const float2* __restrict__ p1,
    const float2* __restrict__ p2, const float* __restrict__ txv,
    const float* __restrict__ tyv, float2* __restrict__ A1,
    float2* __restrict__ A2T, float2* __restrict__ E1, float2* __restrict__ E2) {
  int gid = blockIdx.x*256 + threadIdx.x;          // [0, 524288)
  int o = gid & 255, p = (gid>>8)&7, k = (gid>>11)&15, i = gid>>15;
  float ko = (o < 128) ? (float)o : (float)(o - 256);
  float dty = tyv[1] - tyv[0];
  float dtx = txv[1] - txv[0];
  const float TWO_PI = 6.283185307179586f;
  {
    float lam = TWO_PI * ko / (256.0f * dty);
    float2 pv = p1[(i*16+k)*8 + p];
    float xr = -pv.x, yi = lam - pv.y;
    float D = xr*xr + yi*yi;
    A1[((size_t)((i*16+k)*8 + p))*256 + o] = make_float2(xr/D, -yi/D);
    float tv = tyv[o];
    float m = expf(pv.x*tv);
    E1[((size_t)((i*16+k)*8 + p))*256 + o] = make_float2(m*cosf(pv.y*tv), m*sinf(pv.y*tv));
  }
  {
    float lam = TWO_PI * ko / (256.0f * dtx);
    float2 pv = p2[(i*16+k)*8 + p];
    float xr = -pv.x, yi = lam - pv.y;
    float D = xr*xr + yi*yi;
    A2T[((size_t)i*256 + o)*128 + k*8 + p] = make_float2(xr/D, -yi/D);
    float tv = txv[o];
    float m = expf(pv.x*tv);
    E2[((size_t)((i*16+k)*8 + p))*256 + o] = make_float2(m*cosf(pv.y*tv), m*sinf(pv.y*tv));
  }
}

// ---------------- T[ik][q][o] = sum_p res[ik][p][q] A1[ik][p][o] ------------
__global__ __launch_bounds__(256) void k_T(const float2* __restrict__ res,
    const float2* __restrict__ A1, float2* __restrict__ Tt) {
  int ik = blockIdx.x, tid = threadIdx.x;
  __shared__ float2 rbuf[64];
  __shared__ float2 a1[8][256];
  if (tid < 64) rbuf[tid] = res[(size_t)ik*64 + tid];
  for (int e = 0; e < 8; ++e) {
    int lin = tid + 256*e;
    int p = lin >> 8, o = lin & 255;
    a1[p][o] = A1[((size_t)ik*8 + p)*256 + o];
  }
  __syncthreads();
  int o = tid;
  #pragma unroll
  for (int q = 0; q < 8; ++q) {
    float2 acc = make_float2(0.f, 0.f);
    #pragma unroll
    for (int p = 0; p < 8; ++p) cacc(acc, rbuf[p*8+q], a1[p][o]);
    Tt[((size_t)ik*8 + q)*256 + o] = acc;
  }
}

// ---------------- stats of v (recomputed from x) ----------------------------
__global__ __launch_bounds__(256) void k_stats_v(const float* __restrict__ x,
    const float* __restrict__ fc0w, const float* __restrict__ fc0b,
    float2* __restrict__ stats) {
  int img = blockIdx.x, tid = threadIdx.x;
  int k = img & 15, b = img >> 4;
  float w0 = fc0w[k], w1 = fc0w[16+k], w2 = fc0w[32+k], w3 = fc0w[48+k], w4 = fc0w[64+k];
  float base = fc0b[k] + (tid*(1.0f/255.0f))*w4;
  const float* xb = x + (size_t)b*3*NPIX;
  float s = 0.f, s2 = 0.f;
  for (int it = 0; it < 256; ++it) {
    int p = it*256 + tid;
    float val = base + (it*(1.0f/255.0f))*w3 + xb[p]*w0 + xb[NPIX+p]*w1 + xb[2*NPIX+p]*w2;
    s += val; s2 += val*val;
  }
  __shared__ float rs[256], rq[256];
  rs[tid] = s; rq[tid] = s2;
  __syncthreads();
  for (int off = 128; off > 0; off >>= 1) {
    if (tid < off) { rs[tid] += rs[tid+off]; rq[tid] += rq[tid+off]; }
    __syncthreads();
  }
  if (tid == 0) {
    float mean = rs[0] * (1.0f/65536.0f);
    float var  = rq[0] * (1.0f/65536.0f) - mean*mean;
    stats[img] = make_float2(mean, rsqrtf(var + 1e-5f));
  }
}

// ---------------- stats of a real plane buffer ------------------------------
__global__ __launch_bounds__(256) void k_stats_p(const float* __restrict__ v,
    float2* __restrict__ stats) {
  int img = blockIdx.x, tid = threadIdx.x;
  const float* p = v + (size_t)img*NPIX;
  float s = 0.f, s2 = 0.f;
  for (int it = 0; it < 256; ++it) { float a = p[it*256 + tid]; s += a; s2 += a*a; }
  __shared__ float rs[256], rq[256];
  rs[tid] = s; rq[tid] = s2;
  __syncthreads();
  for (int off = 128; off > 0; off >>= 1) {
    if (tid < off) { rs[tid] += rs[tid+off]; rq[tid] += rq[tid+off]; }
    __syncthreads();
  }
  if (tid == 0) {
    float mean = rs[0] * (1.0f/65536.0f);
    float var  = rq[0] * (1.0f/65536.0f) - mean*mean;
    stats[img] = make_float2(mean, rsqrtf(var + 1e-5f));
  }
}

// ---------------- FFT over rows, input = normalized v recomputed from x -----
__global__ __launch_bounds__(256) void k_fft_v(const float* __restrict__ x,
    const float* __restrict__ fc0w, const float* __restrict__ fc0b,
    const float2* __restrict__ stats, float2* __restrict__ out) {
  __shared__ float sre[4][256], sim[4][256];
  __shared__ float twr[128], twi[128];
  int tid = threadIdx.x, lane = tid & 63, rowi = tid >> 6;
  int bid = blockIdx.x;                  // [0, 8192)
  int img = bid >> 6;
  int h   = (bid & 63)*4 + rowi;
  int k = img & 15, b = img >> 4;
  if (tid < 128) {
    float ang = (PI_F/128.0f)*tid;
    twr[tid] = cosf(ang); twi[tid] = -sinf(ang);
  }
  float2 st = stats[img];
  float w0 = fc0w[k], w1 = fc0w[16+k], w2 = fc0w[32+k], w3 = fc0w[48+k], w4 = fc0w[64+k];
  float bb = fc0b[k] + (h*(1.0f/255.0f))*w3;
  const float* xb = x + (size_t)b*3*NPIX + (size_t)h*256;
  float* re = sre[rowi]; float* im_ = sim[rowi];
  #pragma unroll
  for (int r = 0; r < 4; ++r) {
    int j = lane + 64*r;
    float val = bb + (j*(1.0f/255.0f))*w4 + xb[j]*w0 + xb[NPIX+j]*w1 + xb[2*NPIX+j]*w2;
    val = (val - st.x)*st.y;
    int bj = __brev((unsigned)j) >> 24;
    re[bj] = val; im_[bj] = 0.f;
  }
  fft256(re, im_, twr, twi, lane);
  float2* op = out + ((size_t)img*256 + h)*256;
  #pragma unroll
  for (int r = 0; r < 4; ++r) { int j = lane + 64*r; op[j] = make_float2(re[j], im_[j]); }
}

// ---------------- generic complex row FFT (dir=-1 fwd, +1 inv) --------------
__global__ __launch_bounds__(256) void k_fft_c(const float2* __restrict__ in,
    float2* __restrict__ out, float dir, float scale) {
  __shared__ float sre[4][256], sim[4][256];
  __shared__ float twr[128], twi[128];
  int tid = threadIdx.x, lane = tid & 63, rowi = tid >> 6;
  size_t row = (size_t)blockIdx.x*4 + rowi;      // [0, 32768)
  if (tid < 128) {
    float ang = (PI_F/128.0f)*tid;
    twr[tid] = cosf(ang); twi[tid] = dir*sinf(ang);
  }
  const float2* ip = in + row*256;
  float* re = sre[rowi]; float* im_ = sim[rowi];
  #pragma unroll
  for (int r = 0; r < 4; ++r) {
    int j = lane + 64*r;
    float2 v = ip[j];
    int bj = __brev((unsigned)j) >> 24;
    re[bj] = v.x; im_[bj] = v.y;
  }
  fft256(re, im_, twr, twi, lane);
  float2* op = out + row*256;
  #pragma unroll
  for (int r = 0; r < 4; ++r) { int j = lane + 64*r; op[j] = make_float2(re[j]*scale, im_[j]*scale); }
}

// ---------------- column FFT (in-place), 16 columns per block ---------------
__global__ __launch_bounds__(256) void k_fft_col(float2* __restrict__ buf, float dir) {
  __shared__ float tr[256][17], tim[256][17];
  __shared__ float twr[128], twi[128];
  int tid = threadIdx.x;
  int c = tid & 15, g = tid >> 4;               // column-in-tile, row-group
  int img = blockIdx.x >> 4;
  int c0  = (blockIdx.x & 15) * 16;
  if (tid < 128) {
    float ang = (PI_F/128.0f)*tid;
    twr[tid] = cosf(ang); twi[tid] = dir*sinf(ang);
  }
  float2* base = buf + (size_t)img*NPIX + c0;
  #pragma unroll
  for (int it = 0; it < 16; ++it) {
    int row = it*16 + g;
    float2 v = base[(size_t)row*256 + c];
    int br = __brev((unsigned)row) >> 24;
    tr[br][c] = v.x; tim[br][c] = v.y;
  }
  __syncthreads();
  for (int s = 0; s < 8; ++s) {
    int half = 1 << s;
    #pragma unroll
    for (int r = 0; r < 8; ++r) {
      int m  = g + 16*r;
      int t  = m & (half - 1);
      int grp = m >> s;
      int i0 = (grp << (s+1)) + t;
      int i1 = i0 + half;
      int twx = t << (7 - s);
      float wr = twr[twx], wi = twi[twx];
      float br = tr[i1][c], bi = tim[i1][c];
      float vr = br*wr - bi*wi, vi = br*wi + bi*wr;
      float ar = tr[i0][c], ai = tim[i0][c];
      tr[i0][c] = ar + vr; tim[i0][c] = ai + vi;
      tr[i1][c] = ar - vr; tim[i1][c] = ai - vi;
    }
    __syncthreads();
  }
  #pragma unroll
  for (int it = 0; it < 16; ++it) {
    int row = it*16 + g;
    base[(size_t)row*256 + c] = make_float2(tr[row][c], tim[row][c]);
  }
}

// ---------------- column inverse FFT, write real part to out ---------------
__global__ __launch_bounds__(256) void k_ifft_col_real(const float2* __restrict__ in,
    float* __restrict__ outp, float scale) {
  __shared__ float tr[256][17], tim[256][17];
  __shared__ float twr[128], twi[128];
  int tid = threadIdx.x;
  int c = tid & 15, g = tid >> 4;
  int img = blockIdx.x >> 4;
  int c0  = (blockIdx.x & 15) * 16;
  if (tid < 128) {
    float ang = (PI_F/128.0f)*tid;
    twr[tid] = cosf(ang); twi[tid] = sinf(ang);
  }
  const float2* base = in + (size_t)img*NPIX + c0;
  #pragma unroll
  for (int it = 0; it < 16; ++it) {
    int row = it*16 + g;
    float2 v = base[(size_t)row*256 + c];
    int br = __brev((unsigned)row) >> 24;
    tr[br][c] = v.x; tim[br][c] = v.y;
  }
  __syncthreads();
  for (int s = 0; s < 8; ++s) {
    int half = 1 << s;
    #pragma unroll
    for (int r = 0; r < 8; ++r) {
      int m  = g + 16*r;
      int t  = m & (half - 1);
      int grp = m >> s;
      int i0 = (grp << (s+1)) + t;
      int i1 = i0 + half;
      int twx = t << (7 - s);
      float wr = twr[twx], wi = twi[twx];
      float br = tr[i1][c], bi = tim[i1][c];
      float vr = br*wr - bi*wi, vi = br*wi + bi*wr;
      float ar = tr[i0][c], ai = tim[i0][c];
      tr[i0][c] = ar + vr; tim[i0][c] = ai + vi;
      tr[i1][c] = ar - vr; tim[i1][c] = ai - vi;
    }
    __syncthreads();
  }
  float* ob = outp + (size_t)img*NPIX + c0;
  #pragma unroll
  for (int it = 0; it < 16; ++it) {
    int row = it*16 + g;
    ob[(size_t)row*256 + c] = tr[row][c]*scale;
  }
}

// ---------------- S[n,i,o,(k,q)] = sum_x alpha[n,i,o,x] A2[i,k,q,x] ---------
__global__ __launch_bounds__(256) void k_S(const float2* __restrict__ alpha,
    const float2* __restrict__ A2T, float2* __restrict__ S) {
  __shared__ float2 al[16][256];
  int bid = blockIdx.x;               // (n*16+i)*16 + oblk
  int oblk = bid & 15, ni = bid >> 4;
  int i = ni & 15;
  int tid = threadIdx.x;
  const float2* ap = alpha + ((size_t)ni*256 + oblk*16)*256;
  for (int r = 0; r < 16; ++r) al[r][tid] = ap[(size_t)r*256 + tid];
  __syncthreads();
  int j = tid & 127, oh = tid >> 7;
  float2 acc[8];
  #pragma unroll
  for (int ol = 0; ol < 8; ++ol) acc[ol] = make_float2(0.f, 0.f);
  const float2* a2p = A2T + (size_t)i*32768 + j;
  float2 p0 = a2p[0], p1 = a2p[128], p2 = a2p[256], p3 = a2p[384];
  for (int xx = 0; xx < 256; xx += 4) {
    float2 a0 = p0, a1 = p1, a2v = p2, a3 = p3;
    int nx = xx + 4;
    if (nx < 256) {
      p0 = a2p[(size_t)nx*128];       p1 = a2p[(size_t)(nx+1)*128];
      p2 = a2p[(size_t)(nx+2)*128];   p3 = a2p[(size_t)(nx+3)*128];
    }
    #pragma unroll
    for (int ol = 0; ol < 8; ++ol) {
      cacc(acc[ol], al[oh*8+ol][xx],   a0);
      cacc(acc[ol], al[oh*8+ol][xx+1], a1);
      cacc(acc[ol], al[oh*8+ol][xx+2], a2v);
      cacc(acc[ol], al[oh*8+ol][xx+3], a3);
    }
  }
  #pragma unroll
  for (int ol = 0; ol < 8; ++ol) {
    int o = oblk*16 + oh*8 + ol;
    S[((size_t)ni*256 + o)*128 + j] = acc[ol];
  }
}

// ---------------- Mt[n,i,k,p,q] = sum_o S[n,i,o,(k,q)] A1[i,k,p,o] ----------
__global__ __launch_bounds__(64) void k_Mt(const float2* __restrict__ S,
    const float2* __restrict__ A1, float2* __restrict__ Mt) {
  __shared__ float2 sl[8][258];
  __shared__ float2 a1l[8][258];
  int bid = blockIdx.x;               // (n*16+i)*16 + k
  int k = bid & 15, ni = bid >> 4;
  int i = ni & 15;
  int ik = i*16 + k;
  int tid = threadIdx.x;
  for (int e = 0; e < 32; ++e) {
    int lin = tid + 64*e;             // 0..2047
    int o = lin >> 3, q = lin & 7;
    sl[q][o] = S[((size_t)ni*256 + o)*128 + k*8 + q];
  }
  for (int e = 0; e < 32; ++e) {
    int lin = tid + 64*e;
    int p = lin >> 8, o = lin & 255;
    a1l[p][o] = A1[((size_t)ik*8 + p)*256 + o];
  }
  __syncthreads();
  int p = tid >> 3, q = tid & 7;
  float2 acc = make_float2(0.f, 0.f);
  for (int o = 0; o < 256; ++o) cacc(acc, sl[q][o], a1l[p][o]);
  Mt[(size_t)bid*64 + p*8 + q] = acc;
}

// ---------------- out2[n,k,p,q] = sum_i Mt[n,i,k,p,q] res[i,k,p,q] ----------
__global__ __launch_bounds__(256) void k_out2(const float2* __restrict__ Mt,
    const float2* __restrict__ res, float2* __restrict__ out2) {
  int gid = blockIdx.x*256 + threadIdx.x;   // [0, 8192)
  int pq = gid & 63, k = (gid >> 6) & 15, n = gid >> 10;
  float2 acc = make_float2(0.f, 0.f);
  for (int i = 0; i < 16; ++i)
    cacc(acc, Mt[((size_t)((n*16+i)*16 + k))*64 + pq], res[((size_t)(i*16+k))*64 + pq]);
  out2[((size_t)(n*16+k))*64 + pq] = acc;
}

// ---- fused out1[b,k,o,x] = sum_i alpha[b,i,o,x] (sum_q T[ik,q,o] A2[ik,q,x])
__global__ __launch_bounds__(1024) void k_out1f(const float2* __restrict__ alpha,
    const float2* __restrict__ Tt, const float2* __restrict__ A2T,
    float2* __restrict__ out1) {
  __shared__ float2 sbuf[4096];       // 32 KB: phase1 = T_o[2048], phase2 = al_b[4096]
  int o = blockIdx.x, tid = threadIdx.x;
  int x = tid & 255, kg = tid >> 8;   // kg in [0,4): handles k = kg*4 .. kg*4+3
  // phase 1: gather T at this o
  for (int e = 0; e < 2; ++e) {
    int lin = tid + 1024*e;           // 0..2047 = ik*8+q
    sbuf[lin] = Tt[(size_t)lin*256 + o];
  }
  __syncthreads();
  // build g[kk][i] in registers (fully unrolled -> static indexing)
  float2 g[4][16];
  #pragma unroll
  for (int kk = 0; kk < 4; ++kk) {
    int k = kg*4 + kk;
    #pragma unroll
    for (int i = 0; i < 16; ++i) {
      float2 acc = make_float2(0.f, 0.f);
      const float2* a2 = &A2T[((size_t)i*256 + x)*128 + (size_t)k*8];
      #pragma unroll
      for (int q = 0; q < 8; ++q) cacc(acc, sbuf[(i*16+k)*8 + q], a2[q]);
      g[kk][i] = acc;
    }
  }
  // phase 2: stream batches
  for (int b = 0; b < 8; ++b) {
    __syncthreads();
    for (int e = 0; e < 4; ++e) {
      int lin = tid + 1024*e;         // 0..4095 = i*256 + xx
      int i = lin >> 8, xx = lin & 255;
      sbuf[lin] = alpha[(((size_t)(b*16 + i))*256 + o)*256 + xx];
    }
    __syncthreads();
    #pragma unroll
    for (int kk = 0; kk < 4; ++kk) {
      int k = kg*4 + kk;
      float2 acc = make_float2(0.f, 0.f);
      #pragma unroll
      for (int i = 0; i < 16; ++i) cacc(acc, sbuf[i*256 + x], g[kk][i]);
      out1[(((size_t)(b*16 + k))*256 + o)*256 + x] = acc;
    }
  }
}

// ---------------- U[n,j,kk,q,z] = sum_p out2[n,j,p,q] E1[j,kk,p,z] ----------
__global__ __launch_bounds__(256) void k_U(const float2* __restrict__ out2,
    const float2* __restrict__ E1, float2* __restrict__ U) {
  int bid = blockIdx.x;               // (n*16+j)*16 + kk
  int kk = bid & 15, nj = bid >> 4;
  int j = nj & 15;
  int z = threadIdx.x;
  __shared__ float2 o2[64];
  if (threadIdx.x < 64) o2[threadIdx.x] = out2[(size_t)nj*64 + threadIdx.x];
  __syncthreads();
  float2 e1[8];
  #pragma unroll
  for (int p = 0; p < 8; ++p) e1[p] = E1[(((size_t)(j*16+kk))*8 + p)*256 + z];
  #pragma unroll
  for (int q = 0; q < 8; ++q) {
    float2 acc = make_float2(0.f, 0.f);
    #pragma unroll
    for (int p = 0; p < 8; ++p) cacc(acc, o2[p*8+q], e1[p]);
    U[(((size_t)bid)*8 + q)*256 + z] = acc;
  }
}

// ---------------- x1pre += Re(sum_{j,q} U E2)/65536 -------------------------
__global__ __launch_bounds__(256) void k_x2t(const float2* __restrict__ U,
    const float2* __restrict__ E2, float* __restrict__ x1pre) {
  int bid = blockIdx.x;               // (n*16+kk)*32 + zb
  int zb = bid & 31, nk = bid >> 5;
  int kk = nk & 15, n = nk >> 4;
  int x = threadIdx.x;
  __shared__ float2 ul[1024];         // [j][q][z8]
  for (int e = 0; e < 4; ++e) {
    int lin = threadIdx.x + 256*e;
    int zz = lin & 7, q = (lin >> 3) & 7, j = lin >> 6;
    ul[lin] = U[((((size_t)(n*16+j))*16 + kk)*8 + q)*256 + zb*8 + zz];
  }
  __syncthreads();
  float acc[8] = {0.f,0.f,0.f,0.f,0.f,0.f,0.f,0.f};
  const float2* e2b = E2 + (size_t)kk*2048 + x;   // addr(j,q) = j*32768 + q*256
  float2 nxt = e2b[0];
  for (int jq = 0; jq < 128; ++jq) {
    float2 e2 = nxt;
    int njq = jq + 1;
    if (njq < 128) {
      int nj = njq >> 3, nq = njq & 7;
      nxt = e2b[(size_t)nj*32768 + (size_t)nq*256];
    }
    const float2* up = &ul[jq*8];
    #pragma unroll
    for (int zz = 0; zz < 8; ++zz) {
      float2 u = up[zz];
      acc[zz] = fmaf(u.x, e2.x, fmaf(-u.y, e2.y, acc[zz]));
    }
  }
  const float sc = 1.0f/65536.0f;
  #pragma unroll
  for (int zz = 0; zz < 8; ++zz) {
    size_t idx = (((size_t)nk)*256 + zb*8 + zz)*256 + x;
    x1pre[idx] += acc[zz]*sc;
  }
}

// ---------------- final: inorm(x1pre) + w0conv(v) -> fc1 -> sin -> fc2 ------
__global__ __launch_bounds__(256) void k_final(const float* __restrict__ x,
    const float* __restrict__ x1pre, const float2* __restrict__ stats2,
    const float* __restrict__ fc0w, const float* __restrict__ fc0b,
    const float* __restrict__ w0w, const float* __restrict__ w0b,
    const float* __restrict__ fc1w, const float* __restrict__ fc1b,
    const float* __restrict__ fc2w, const float* __restrict__ fc2b,
    float* __restrict__ out) {
  __shared__ float s_fc1w[2048], s_fc1b[128], s_fc2w[384], s_w0w[256], s_w0b[16], s_fc2b[3];
  int tid = threadIdx.x;
  for (int e = 0; e < 8; ++e) s_fc1w[tid + 256*e] = fc1w[tid + 256*e];
  if (tid < 128) s_fc1b[tid] = fc1b[tid];
  for (int e = 0; e < 2; ++e) { int q = tid + 256*e; if (q < 384) s_fc2w[q] = fc2w[q]; }
  s_w0w[tid] = w0w[tid];
  if (tid < 16) s_w0b[tid] = w0b[tid];
  if (tid < 3)  s_fc2b[tid] = fc2b[tid];
  __syncthreads();

  int bid = blockIdx.x;               // b*256 + h
  int hh = bid & 255, b = bid >> 8;
  int ww = tid;
  size_t pix = (size_t)hh*256 + ww;
  float xc0 = x[((size_t)b*3 + 0)*NPIX + pix];
  float xc1 = x[((size_t)b*3 + 1)*NPIX + pix];
  float xc2 = x[((size_t)b*3 + 2)*NPIX + pix];
  float gx = hh*(1.0f/255.0f), gy = ww*(1.0f/255.0f);
  float v[16], x1n[16], uo[16];
  #pragma unroll
  for (int k = 0; k < 16; ++k)
    v[k] = fc0b[k] + xc0*fc0w[k] + xc1*fc0w[16+k] + xc2*fc0w[32+k] + gx*fc0w[48+k] + gy*fc0w[64+k];
  #pragma unroll
  for (int k = 0; k < 16; ++k) {
    float2 st = stats2[b*16 + k];
    float xv = x1pre[((size_t)(b*16 + k))*NPIX + pix];
    x1n[k] = (xv - st.x)*st.y;
  }
  #pragma unroll
  for (int o = 0; o < 16; ++o) {
    float acc = s_w0b[o];
    #pragma unroll
    for (int k = 0; k < 16; ++k) acc = fmaf(v[k], s_w0w[o*16+k], acc);
    uo[o] = acc + x1n[o];
  }
  float o0 = 0.f, o1 = 0.f, o2 = 0.f;
  for (int jj = 0; jj < 128; ++jj) {
    float t = s_fc1b[jj];
    #pragma unroll
    for (int k = 0; k < 16; ++k) t = fmaf(uo[k], s_fc1w[k*128 + jj], t);
    float s = __sinf(t);
    o0 = fmaf(s, s_fc2w[jj*3+0], o0);
    o1 = fmaf(s, s_fc2w[jj*3+1], o1);
    o2 = fmaf(s, s_fc2w[jj*3+2], o2);
  }
  out[((size_t)b*3 + 0)*NPIX + pix] = o0 + s_fc2b[0];
  out[((size_t)b*3 + 1)*NPIX + pix] = o1 + s_fc2b[1];
  out[((size_t)b*3 + 2)*NPIX + pix] = o2 + s_fc2b[2];
}

// ---------------------------------------------------------------------------
extern "C" void kernel_launch(void* const* d_in, const int* in_sizes, int n_in,
                              void* d_out, int out_size, void* d_ws, size_t ws_size,
                              hipStream_t stream) {
  const float*  x    = (const float*)d_in[0];
  const float*  fc0w = (const float*)d_in[1];
  const float*  fc0b = (const float*)d_in[2];
  const float2* p1   = (const float2*)d_in[3];
  const float2* p2   = (const float2*)d_in[4];
  const float2* res  = (const float2*)d_in[5];
  const float*  w0w  = (const float*)d_in[6];
  const float*  w0b  = (const float*)d_in[7];
  const float*  fc1w = (const float*)d_in[8];
  const float*  fc1b = (const float*)d_in[9];
  const float*  fc2w = (const float*)d_in[10];
  const float*  fc2b = (const float*)d_in[11];
  const float*  txv  = (const float*)d_in[12];
  const float*  tyv  = (const float*)d_in[13];
  float* out = (float*)d_out;

  // workspace layout (bytes); NEED == proven-safe 252,774,400
  const size_t OFF_A1   = 0;            // 4 MiB
  const size_t OFF_A2T  = 4194304;      // 4 MiB
  const size_t OFF_E1   = 8388608;      // 4 MiB
  const size_t OFF_E2   = 12582912;     // 4 MiB
  const size_t OFF_ST1  = 16777216;
  const size_t OFF_ST2  = 16778240;
  const size_t OFF_OUT2 = 16779264;     // 64 KiB
  const size_t OFF_MT   = 16844800;     // 1 MiB
  const size_t OFF_S    = 17893376;     // 32 MiB  (S)
  const size_t OFF_X1   = 51447808;     // 32 MiB  (Tt 4MiB early; X1 real later)
  const size_t OFF_A    = 85002240;     // 64 MiB  (spectrum ping / alpha)
  const size_t OFF_B    = 152111104;    // 64 MiB  (out1)
  const size_t OFF_G    = 219219968;    // 32 MiB  (U)
  const size_t NEED     = 252774400;
  if (ws_size < NEED) return;
  char* ws = (char*)d_ws;
  float2* A1  = (float2*)(ws + OFF_A1);
  float2* A2T = (float2*)(ws + OFF_A2T);
  float2* E1  = (float2*)(ws + OFF_E1);
  float2* E2  = (float2*)(ws + OFF_E2);
  float2* st1 = (float2*)(ws + OFF_ST1);
  float2* st2 = (float2*)(ws + OFF_ST2);
  float2* o2b = (float2*)(ws + OFF_OUT2);
  float2* Mt  = (float2*)(ws + OFF_MT);
  float2* Sb  = (float2*)(ws + OFF_S);
  float2* Tt  = (float2*)(ws + OFF_X1);   // dead before X1 is written
  float*  X1  = (float*)(ws + OFF_X1);
  float2* Ab  = (float2*)(ws + OFF_A);
  float2* Bb  = (float2*)(ws + OFF_B);
  float2* Ub  = (float2*)(ws + OFF_G);

  k_setup  <<<2048, 256, 0, stream>>>(p1, p2, txv, tyv, A1, A2T, E1, E2);
  k_T      <<<256, 256, 0, stream>>>(res, A1, Tt);
  k_stats_v<<<128, 256, 0, stream>>>(x, fc0w, fc0b, st1);
  // forward fft2: rows then columns (in place) -> alpha in Ab
  k_fft_v  <<<8192, 256, 0, stream>>>(x, fc0w, fc0b, st1, Ab);
  k_fft_col<<<2048, 256, 0, stream>>>(Ab, -1.f);                // Ab = alpha [b,i,o,x]
  // pole-residue spectral sums
  k_S      <<<2048, 256, 0, stream>>>(Ab, A2T, Sb);
  k_Mt     <<<2048, 64, 0, stream>>>(Sb, A1, Mt);
  k_out2   <<<32, 256, 0, stream>>>(Mt, res, o2b);
  // fused out1 (G built on the fly)
  k_out1f  <<<256, 1024, 0, stream>>>(Ab, Tt, A2T, Bb);         // Bb = out1
  // inverse fft2: rows then columns, real output
  k_fft_c  <<<8192, 256, 0, stream>>>(Bb, Ab, +1.f, 1.f);       // ifft over x
  k_ifft_col_real<<<2048, 256, 0, stream>>>(Ab, X1, 1.0f/65536.0f); // X1 [img][h][w]
  // transient part added into x1pre
  k_U      <<<2048, 256, 0, stream>>>(o2b, E1, Ub);
  k_x2t    <<<4096, 256, 0, stream>>>(Ub, E2, X1);
  // second instance norm + heads
  k_stats_p<<<128, 256, 0, stream>>>(X1, st2);
  k_final  <<<2048, 256, 0, stream>>>(x, X1, st2, fc0w, fc0b,
                                      w0w, w0b, fc1w, fc1b, fc2w, fc2b, out);
}

// Round 4
// 779.865 us; speedup vs baseline: 1.1127x; 1.1127x over previous
//
#include <hip/hip_runtime.h>
#include <cstddef>

#define NPIX 65536
#define PI_F 3.14159265358979323846f

__device__ __forceinline__ void cacc(float2& acc, float2 a, float2 b) {
  acc.x = fmaf(a.x, b.x, fmaf(-a.y, b.y, acc.x));
  acc.y = fmaf(a.x, b.y, fmaf(a.y, b.x, acc.y));
}

// ---------------- 256-point radix-2 DIT FFT in LDS (one wave per line) -----
__device__ __forceinline__ void fft256(float* re, float* im, const float* twr,
                                       const float* twi, int lane) {
  #pragma unroll
  for (int s = 0; s < 8; ++s) {
    __syncthreads();
    const int half = 1 << s;
    #pragma unroll
    for (int r = 0; r < 2; ++r) {
      int m  = lane + 64*r;
      int t  = m & (half - 1);
      int g  = m >> s;
      int i0 = (g << (s+1)) + t;
      int i1 = i0 + half;
      int ti = t << (7 - s);
      float wr = twr[ti], wi = twi[ti];
      float br = re[i1], bi = im[i1];
      float vr = br*wr - bi*wi;
      float vi = br*wi + bi*wr;
      float ar = re[i0], ai = im[i0];
      re[i0] = ar + vr; im[i0] = ai + vi;
      re[i1] = ar - vr; im[i1] = ai - vi;
    }
  }
  __syncthreads();
}

// ---------------- setup: A1, A2T, E1, E2 ------------------------------------
__global__ __launch_bounds__(256) void k_setup(const float2* __restrict__ p1,
    const float2* __restrict__ p2, const float* __restrict__ txv,
    const float* __restrict__ tyv, float2* __restrict__ A1,
    float2* __restrict__ A2T, float2* __restrict__ E1, float2* __restrict__ E2) {
  int gid = blockIdx.x*256 + threadIdx.x;          // [0, 524288)
  int o = gid & 255, p = (gid>>8)&7, k = (gid>>11)&15, i = gid>>15;
  float ko = (o < 128) ? (float)o : (float)(o - 256);
  float dty = tyv[1] - tyv[0];
  float dtx = txv[1] - txv[0];
  const float TWO_PI = 6.283185307179586f;
  {
    float lam = TWO_PI * ko / (256.0f * dty);
    float2 pv = p1[(i*16+k)*8 + p];
    float xr = -pv.x, yi = lam - pv.y;
    float D = xr*xr + yi*yi;
    A1[((size_t)((i*16+k)*8 + p))*256 + o] = make_float2(xr/D, -yi/D);
    float tv = tyv[o];
    float m = expf(pv.x*tv);
    E1[((size_t)((i*16+k)*8 + p))*256 + o] = make_float2(m*cosf(pv.y*tv), m*sinf(pv.y*tv));
  }
  {
    float lam = TWO_PI * ko / (256.0f * dtx);
    float2 pv = p2[(i*16+k)*8 + p];
    float xr = -pv.x, yi = lam - pv.y;
    float D = xr*xr + yi*yi;
    A2T[((size_t)i*256 + o)*128 + k*8 + p] = make_float2(xr/D, -yi/D);
    float tv = txv[o];
    float m = expf(pv.x*tv);
    E2[((size_t)((i*16+k)*8 + p))*256 + o] = make_float2(m*cosf(pv.y*tv), m*sinf(pv.y*tv));
  }
}

// ---------------- T[ik][q][o] = sum_p res[ik][p][q] A1[ik][p][o] ------------
__global__ __launch_bounds__(256) void k_T(const float2* __restrict__ res,
    const float2* __restrict__ A1, float2* __restrict__ Tt) {
  int ik = blockIdx.x, tid = threadIdx.x;
  __shared__ float2 rbuf[64];
  __shared__ float2 a1[8][256];
  if (tid < 64) rbuf[tid] = res[(size_t)ik*64 + tid];
  for (int e = 0; e < 8; ++e) {
    int lin = tid + 256*e;
    int p = lin >> 8, o = lin & 255;
    a1[p][o] = A1[((size_t)ik*8 + p)*256 + o];
  }
  __syncthreads();
  int o = tid;
  #pragma unroll
  for (int q = 0; q < 8; ++q) {
    float2 acc = make_float2(0.f, 0.f);
    #pragma unroll
    for (int p = 0; p < 8; ++p) cacc(acc, rbuf[p*8+q], a1[p][o]);
    Tt[((size_t)ik*8 + q)*256 + o] = acc;
  }
}

// ---------------- stats of v (recomputed from x) ----------------------------
__global__ __launch_bounds__(256) void k_stats_v(const float* __restrict__ x,
    const float* __restrict__ fc0w, const float* __restrict__ fc0b,
    float2* __restrict__ stats) {
  int img = blockIdx.x, tid = threadIdx.x;
  int k = img & 15, b = img >> 4;
  float w0 = fc0w[k], w1 = fc0w[16+k], w2 = fc0w[32+k], w3 = fc0w[48+k], w4 = fc0w[64+k];
  float base = fc0b[k] + (tid*(1.0f/255.0f))*w4;
  const float* xb = x + (size_t)b*3*NPIX;
  float s = 0.f, s2 = 0.f;
  for (int it = 0; it < 256; ++it) {
    int p = it*256 + tid;
    float val = base + (it*(1.0f/255.0f))*w3 + xb[p]*w0 + xb[NPIX+p]*w1 + xb[2*NPIX+p]*w2;
    s += val; s2 += val*val;
  }
  __shared__ float rs[256], rq[256];
  rs[tid] = s; rq[tid] = s2;
  __syncthreads();
  for (int off = 128; off > 0; off >>= 1) {
    if (tid < off) { rs[tid] += rs[tid+off]; rq[tid] += rq[tid+off]; }
    __syncthreads();
  }
  if (tid == 0) {
    float mean = rs[0] * (1.0f/65536.0f);
    float var  = rq[0] * (1.0f/65536.0f) - mean*mean;
    stats[img] = make_float2(mean, rsqrtf(var + 1e-5f));
  }
}

// ---------------- stats of a real plane buffer ------------------------------
__global__ __launch_bounds__(256) void k_stats_p(const float* __restrict__ v,
    float2* __restrict__ stats) {
  int img = blockIdx.x, tid = threadIdx.x;
  const float* p = v + (size_t)img*NPIX;
  float s = 0.f, s2 = 0.f;
  for (int it = 0; it < 256; ++it) { float a = p[it*256 + tid]; s += a; s2 += a*a; }
  __shared__ float rs[256], rq[256];
  rs[tid] = s; rq[tid] = s2;
  __syncthreads();
  for (int off = 128; off > 0; off >>= 1) {
    if (tid < off) { rs[tid] += rs[tid+off]; rq[tid] += rq[tid+off]; }
    __syncthreads();
  }
  if (tid == 0) {
    float mean = rs[0] * (1.0f/65536.0f);
    float var  = rq[0] * (1.0f/65536.0f) - mean*mean;
    stats[img] = make_float2(mean, rsqrtf(var + 1e-5f));
  }
}

// ---------------- FFT over rows, input = normalized v recomputed from x -----
__global__ __launch_bounds__(256) void k_fft_v(const float* __restrict__ x,
    const float* __restrict__ fc0w, const float* __restrict__ fc0b,
    const float2* __restrict__ stats, float2* __restrict__ out) {
  __shared__ float sre[4][256], sim[4][256];
  __shared__ float twr[128], twi[128];
  int tid = threadIdx.x, lane = tid & 63, rowi = tid >> 6;
  int bid = blockIdx.x;                  // [0, 8192)
  int img = bid >> 6;
  int h   = (bid & 63)*4 + rowi;
  int k = img & 15, b = img >> 4;
  if (tid < 128) {
    float ang = (PI_F/128.0f)*tid;
    twr[tid] = cosf(ang); twi[tid] = -sinf(ang);
  }
  float2 st = stats[img];
  float w0 = fc0w[k], w1 = fc0w[16+k], w2 = fc0w[32+k], w3 = fc0w[48+k], w4 = fc0w[64+k];
  float bb = fc0b[k] + (h*(1.0f/255.0f))*w3;
  const float* xb = x + (size_t)b*3*NPIX + (size_t)h*256;
  float* re = sre[rowi]; float* im_ = sim[rowi];
  #pragma unroll
  for (int r = 0; r < 4; ++r) {
    int j = lane + 64*r;
    float val = bb + (j*(1.0f/255.0f))*w4 + xb[j]*w0 + xb[NPIX+j]*w1 + xb[2*NPIX+j]*w2;
    val = (val - st.x)*st.y;
    int bj = __brev((unsigned)j) >> 24;
    re[bj] = val; im_[bj] = 0.f;
  }
  fft256(re, im_, twr, twi, lane);
  float2* op = out + ((size_t)img*256 + h)*256;
  #pragma unroll
  for (int r = 0; r < 4; ++r) { int j = lane + 64*r; op[j] = make_float2(re[j], im_[j]); }
}

// ---------------- generic complex row FFT (dir=-1 fwd, +1 inv) --------------
__global__ __launch_bounds__(256) void k_fft_c(const float2* __restrict__ in,
    float2* __restrict__ out, float dir, float scale) {
  __shared__ float sre[4][256], sim[4][256];
  __shared__ float twr[128], twi[128];
  int tid = threadIdx.x, lane = tid & 63, rowi = tid >> 6;
  size_t row = (size_t)blockIdx.x*4 + rowi;      // [0, 32768)
  if (tid < 128) {
    float ang = (PI_F/128.0f)*tid;
    twr[tid] = cosf(ang); twi[tid] = dir*sinf(ang);
  }
  const float2* ip = in + row*256;
  float* re = sre[rowi]; float* im_ = sim[rowi];
  #pragma unroll
  for (int r = 0; r < 4; ++r) {
    int j = lane + 64*r;
    float2 v = ip[j];
    int bj = __brev((unsigned)j) >> 24;
    re[bj] = v.x; im_[bj] = v.y;
  }
  fft256(re, im_, twr, twi, lane);
  float2* op = out + row*256;
  #pragma unroll
  for (int r = 0; r < 4; ++r) { int j = lane + 64*r; op[j] = make_float2(re[j]*scale, im_[j]*scale); }
}

// ---------------- column FFT (in-place), 16 columns per block ---------------
__global__ __launch_bounds__(256) void k_fft_col(float2* __restrict__ buf, float dir) {
  __shared__ float tr[256][17], tim[256][17];
  __shared__ float twr[128], twi[128];
  int tid = threadIdx.x;
  int c = tid & 15, g = tid >> 4;               // column-in-tile, row-group
  int img = blockIdx.x >> 4;
  int c0  = (blockIdx.x & 15) * 16;
  if (tid < 128) {
    float ang = (PI_F/128.0f)*tid;
    twr[tid] = cosf(ang); twi[tid] = dir*sinf(ang);
  }
  float2* base = buf + (size_t)img*NPIX + c0;
  #pragma unroll
  for (int it = 0; it < 16; ++it) {
    int row = it*16 + g;
    float2 v = base[(size_t)row*256 + c];
    int br = __brev((unsigned)row) >> 24;
    tr[br][c] = v.x; tim[br][c] = v.y;
  }
  __syncthreads();
  for (int s = 0; s < 8; ++s) {
    int half = 1 << s;
    #pragma unroll
    for (int r = 0; r < 8; ++r) {
      int m  = g + 16*r;
      int t  = m & (half - 1);
      int grp = m >> s;
      int i0 = (grp << (s+1)) + t;
      int i1 = i0 + half;
      int twx = t << (7 - s);
      float wr = twr[twx], wi = twi[twx];
      float br = tr[i1][c], bi = tim[i1][c];
      float vr = br*wr - bi*wi, vi = br*wi + bi*wr;
      float ar = tr[i0][c], ai = tim[i0][c];
      tr[i0][c] = ar + vr; tim[i0][c] = ai + vi;
      tr[i1][c] = ar - vr; tim[i1][c] = ai - vi;
    }
    __syncthreads();
  }
  #pragma unroll
  for (int it = 0; it < 16; ++it) {
    int row = it*16 + g;
    base[(size_t)row*256 + c] = make_float2(tr[row][c], tim[row][c]);
  }
}

// ---------------- column inverse FFT, write real part to out ---------------
__global__ __launch_bounds__(256) void k_ifft_col_real(const float2* __restrict__ in,
    float* __restrict__ outp, float scale) {
  __shared__ float tr[256][17], tim[256][17];
  __shared__ float twr[128], twi[128];
  int tid = threadIdx.x;
  int c = tid & 15, g = tid >> 4;
  int img = blockIdx.x >> 4;
  int c0  = (blockIdx.x & 15) * 16;
  if (tid < 128) {
    float ang = (PI_F/128.0f)*tid;
    twr[tid] = cosf(ang); twi[tid] = sinf(ang);
  }
  const float2* base = in + (size_t)img*NPIX + c0;
  #pragma unroll
  for (int it = 0; it < 16; ++it) {
    int row = it*16 + g;
    float2 v = base[(size_t)row*256 + c];
    int br = __brev((unsigned)row) >> 24;
    tr[br][c] = v.x; tim[br][c] = v.y;
  }
  __syncthreads();
  for (int s = 0; s < 8; ++s) {
    int half = 1 << s;
    #pragma unroll
    for (int r = 0; r < 8; ++r) {
      int m  = g + 16*r;
      int t  = m & (half - 1);
      int grp = m >> s;
      int i0 = (grp << (s+1)) + t;
      int i1 = i0 + half;
      int twx = t << (7 - s);
      float wr = twr[twx], wi = twi[twx];
      float br = tr[i1][c], bi = tim[i1][c];
      float vr = br*wr - bi*wi, vi = br*wi + bi*wr;
      float ar = tr[i0][c], ai = tim[i0][c];
      tr[i0][c] = ar + vr; tim[i0][c] = ai + vi;
      tr[i1][c] = ar - vr; tim[i1][c] = ai - vi;
    }
    __syncthreads();
  }
  float* ob = outp + (size_t)img*NPIX + c0;
  #pragma unroll
  for (int it = 0; it < 16; ++it) {
    int row = it*16 + g;
    ob[(size_t)row*256 + c] = tr[row][c]*scale;
  }
}

// ---------------- S[n,i,o,(k,q)] = sum_x alpha[n,i,o,x] A2[i,k,q,x] ---------
__global__ __launch_bounds__(256) void k_S(const float2* __restrict__ alpha,
    const float2* __restrict__ A2T, float2* __restrict__ S) {
  __shared__ float2 al[16][256];
  int bid = blockIdx.x;               // (n*16+i)*16 + oblk
  int oblk = bid & 15, ni = bid >> 4;
  int i = ni & 15;
  int tid = threadIdx.x;
  const float2* ap = alpha + ((size_t)ni*256 + oblk*16)*256;
  for (int r = 0; r < 16; ++r) al[r][tid] = ap[(size_t)r*256 + tid];
  __syncthreads();
  int j = tid & 127, oh = tid >> 7;
  float2 acc[8];
  #pragma unroll
  for (int ol = 0; ol < 8; ++ol) acc[ol] = make_float2(0.f, 0.f);
  const float2* a2p = A2T + (size_t)i*32768 + j;
  float2 p0 = a2p[0], p1 = a2p[128], p2 = a2p[256], p3 = a2p[384];
  for (int xx = 0; xx < 256; xx += 4) {
    float2 a0 = p0, a1 = p1, a2v = p2, a3 = p3;
    int nx = xx + 4;
    if (nx < 256) {
      p0 = a2p[(size_t)nx*128];       p1 = a2p[(size_t)(nx+1)*128];
      p2 = a2p[(size_t)(nx+2)*128];   p3 = a2p[(size_t)(nx+3)*128];
    }
    #pragma unroll
    for (int ol = 0; ol < 8; ++ol) {
      cacc(acc[ol], al[oh*8+ol][xx],   a0);
      cacc(acc[ol], al[oh*8+ol][xx+1], a1);
      cacc(acc[ol], al[oh*8+ol][xx+2], a2v);
      cacc(acc[ol], al[oh*8+ol][xx+3], a3);
    }
  }
  #pragma unroll
  for (int ol = 0; ol < 8; ++ol) {
    int o = oblk*16 + oh*8 + ol;
    S[((size_t)ni*256 + o)*128 + j] = acc[ol];
  }
}

// ---------------- Mt[n,i,k,p,q] = sum_o S[n,i,o,(k,q)] A1[i,k,p,o] ----------
__global__ __launch_bounds__(256) void k_Mt(const float2* __restrict__ S,
    const float2* __restrict__ A1, float2* __restrict__ Mt) {
  __shared__ float2 sl[8][258];
  __shared__ float2 a1l[8][258];
  __shared__ float2 part[4][64];
  int bid = blockIdx.x;               // (n*16+i)*16 + k
  int k = bid & 15, ni = bid >> 4;
  int i = ni & 15;
  int ik = i*16 + k;
  int tid = threadIdx.x;
  for (int e = 0; e < 8; ++e) {
    int lin = tid + 256*e;            // 0..2047
    int o = lin >> 3, q = lin & 7;
    sl[q][o] = S[((size_t)ni*256 + o)*128 + k*8 + q];
  }
  for (int e = 0; e < 8; ++e) {
    int lin = tid + 256*e;
    int p = lin >> 8, o = lin & 255;
    a1l[p][o] = A1[((size_t)ik*8 + p)*256 + o];
  }
  __syncthreads();
  int oq = tid >> 6, pq = tid & 63, p = pq >> 3, q = pq & 7;
  float2 acc = make_float2(0.f, 0.f);
  int o0 = oq*64;
  for (int o = o0; o < o0 + 64; ++o) cacc(acc, sl[q][o], a1l[p][o]);
  part[oq][pq] = acc;
  __syncthreads();
  if (oq == 0) {
    float2 a = part[0][pq], b = part[1][pq], c = part[2][pq], d = part[3][pq];
    acc.x = a.x + b.x + c.x + d.x;
    acc.y = a.y + b.y + c.y + d.y;
    Mt[(size_t)bid*64 + pq] = acc;
  }
}

// ---------------- out2[n,k,p,q] = sum_i Mt[n,i,k,p,q] res[i,k,p,q] ----------
__global__ __launch_bounds__(256) void k_out2(const float2* __restrict__ Mt,
    const float2* __restrict__ res, float2* __restrict__ out2) {
  int gid = blockIdx.x*256 + threadIdx.x;   // [0, 8192)
  int pq = gid & 63, k = (gid >> 6) & 15, n = gid >> 10;
  float2 acc = make_float2(0.f, 0.f);
  for (int i = 0; i < 16; ++i)
    cacc(acc, Mt[((size_t)((n*16+i)*16 + k))*64 + pq], res[((size_t)(i*16+k))*64 + pq]);
  out2[((size_t)(n*16+k))*64 + pq] = acc;
}

// ---- fused out1: block = (o, k-pair); g kept in 64 VGPRs, no LDS streaming -
// out1[b,k,o,x] = sum_i alpha[b,i,o,x] * g_k[i](x),
// g_k[i](x) = sum_q T[ik,q,o] A2T[i,x,(k,q)]
__global__ __launch_bounds__(256) void k_out1g(const float2* __restrict__ alpha,
    const float2* __restrict__ Tt, const float2* __restrict__ A2T,
    float2* __restrict__ out1) {
  // XCD-aware mapping: dispatch d -> xcd = d&7 owns o in [xcd*32, xcd*32+32)
  int d = blockIdx.x;                 // [0, 2048)
  int xcd = d & 7, idx = d >> 3;      // idx [0, 256)
  int o  = xcd*32 + (idx >> 3);
  int kh = idx & 7;                   // k pair: 2*kh, 2*kh+1
  int x = threadIdx.x;
  __shared__ float2 tl[2][128];       // T[i,q] at (2*kh+kk, o)
  {
    int t = threadIdx.x;              // 256 threads -> 256 entries
    int kk = t >> 7, rem = t & 127;
    int i = rem >> 3, q = rem & 7;
    tl[kk][rem] = Tt[((size_t)((i*16 + 2*kh + kk)*8 + q))*256 + o];
  }
  __syncthreads();
  float2 g0[16], g1[16];
  #pragma unroll
  for (int i = 0; i < 16; ++i) {
    const float2* a2 = &A2T[((size_t)i*256 + x)*128 + kh*16];
    float2 acc0 = make_float2(0.f, 0.f), acc1 = make_float2(0.f, 0.f);
    #pragma unroll
    for (int q = 0; q < 8; ++q) {
      cacc(acc0, tl[0][i*8+q], a2[q]);
      cacc(acc1, tl[1][i*8+q], a2[8+q]);
    }
    g0[i] = acc0; g1[i] = acc1;
  }
  for (int b = 0; b < 8; ++b) {
    float2 acc0 = make_float2(0.f, 0.f), acc1 = make_float2(0.f, 0.f);
    #pragma unroll
    for (int i = 0; i < 16; ++i) {
      float2 al = alpha[(((size_t)(b*16 + i))*256 + o)*256 + x];
      cacc(acc0, al, g0[i]);
      cacc(acc1, al, g1[i]);
    }
    out1[(((size_t)(b*16 + 2*kh + 0))*256 + o)*256 + x] = acc0;
    out1[(((size_t)(b*16 + 2*kh + 1))*256 + o)*256 + x] = acc1;
  }
}

// ---------------- U[n,j,kk,q,z] = sum_p out2[n,j,p,q] E1[j,kk,p,z] ----------
__global__ __launch_bounds__(256) void k_U(const float2* __restrict__ out2,
    const float2* __restrict__ E1, float2* __restrict__ U) {
  int bid = blockIdx.x;               // (n*16+j)*16 + kk
  int kk = bid & 15, nj = bid >> 4;
  int j = nj & 15;
  int z = threadIdx.x;
  __shared__ float2 o2[64];
  if (threadIdx.x < 64) o2[threadIdx.x] = out2[(size_t)nj*64 + threadIdx.x];
  __syncthreads();
  float2 e1[8];
  #pragma unroll
  for (int p = 0; p < 8; ++p) e1[p] = E1[(((size_t)(j*16+kk))*8 + p)*256 + z];
  #pragma unroll
  for (int q = 0; q < 8; ++q) {
    float2 acc = make_float2(0.f, 0.f);
    #pragma unroll
    for (int p = 0; p < 8; ++p) cacc(acc, o2[p*8+q], e1[p]);
    U[(((size_t)bid)*8 + q)*256 + z] = acc;
  }
}

// ---------------- x1pre += Re(sum_{j,q} U E2)/65536 -------------------------
__global__ __launch_bounds__(256) void k_x2t(const float2* __restrict__ U,
    const float2* __restrict__ E2, float* __restrict__ x1pre) {
  int bid = blockIdx.x;               // (n*16+kk)*32 + zb
  int zb = bid & 31, nk = bid >> 5;
  int kk = nk & 15, n = nk >> 4;
  int x = threadIdx.x;
  __shared__ float2 ul[1024];         // [j][q][z8]
  for (int e = 0; e < 4; ++e) {
    int lin = threadIdx.x + 256*e;
    int zz = lin & 7, q = (lin >> 3) & 7, j = lin >> 6;
    ul[lin] = U[((((size_t)(n*16+j))*16 + kk)*8 + q)*256 + zb*8 + zz];
  }
  __syncthreads();
  float acc[8] = {0.f,0.f,0.f,0.f,0.f,0.f,0.f,0.f};
  const float2* e2b = E2 + (size_t)kk*2048 + x;   // addr(j,q) = j*32768 + q*256
  float2 nxt = e2b[0];
  for (int jq = 0; jq < 128; ++jq) {
    float2 e2 = nxt;
    int njq = jq + 1;
    if (njq < 128) {
      int nj = njq >> 3, nq = njq & 7;
      nxt = e2b[(size_t)nj*32768 + (size_t)nq*256];
    }
    const float2* up = &ul[jq*8];
    #pragma unroll
    for (int zz = 0; zz < 8; ++zz) {
      float2 u = up[zz];
      acc[zz] = fmaf(u.x, e2.x, fmaf(-u.y, e2.y, acc[zz]));
    }
  }
  const float sc = 1.0f/65536.0f;
  #pragma unroll
  for (int zz = 0; zz < 8; ++zz) {
    size_t idx = (((size_t)nk)*256 + zb*8 + zz)*256 + x;
    x1pre[idx] += acc[zz]*sc;
  }
}

// ---------------- final: inorm(x1pre) + w0conv(v) -> fc1 -> sin -> fc2 ------
__global__ __launch_bounds__(256) void k_final(const float* __restrict__ x,
    const float* __restrict__ x1pre, const float2* __restrict__ stats2,
    const float* __restrict__ fc0w, const float* __restrict__ fc0b,
    const float* __restrict__ w0w, const float* __restrict__ w0b,
    const float* __restrict__ fc1w, const float* __restrict__ fc1b,
    const float* __restrict__ fc2w, const float* __restrict__ fc2b,
    float* __restrict__ out) {
  __shared__ float s_fc1w[2048], s_fc1b[128], s_fc2w[384], s_w0w[256], s_w0b[16], s_fc2b[3];
  int tid = threadIdx.x;
  for (int e = 0; e < 8; ++e) s_fc1w[tid + 256*e] = fc1w[tid + 256*e];
  if (tid < 128) s_fc1b[tid] = fc1b[tid];
  for (int e = 0; e < 2; ++e) { int q = tid + 256*e; if (q < 384) s_fc2w[q] = fc2w[q]; }
  s_w0w[tid] = w0w[tid];
  if (tid < 16) s_w0b[tid] = w0b[tid];
  if (tid < 3)  s_fc2b[tid] = fc2b[tid];
  __syncthreads();

  int bid = blockIdx.x;               // b*256 + h
  int hh = bid & 255, b = bid >> 8;
  int ww = tid;
  size_t pix = (size_t)hh*256 + ww;
  float xc0 = x[((size_t)b*3 + 0)*NPIX + pix];
  float xc1 = x[((size_t)b*3 + 1)*NPIX + pix];
  float xc2 = x[((size_t)b*3 + 2)*NPIX + pix];
  float gx = hh*(1.0f/255.0f), gy = ww*(1.0f/255.0f);
  float v[16], x1n[16], uo[16];
  #pragma unroll
  for (int k = 0; k < 16; ++k)
    v[k] = fc0b[k] + xc0*fc0w[k] + xc1*fc0w[16+k] + xc2*fc0w[32+k] + gx*fc0w[48+k] + gy*fc0w[64+k];
  #pragma unroll
  for (int k = 0; k < 16; ++k) {
    float2 st = stats2[b*16 + k];
    float xv = x1pre[((size_t)(b*16 + k))*NPIX + pix];
    x1n[k] = (xv - st.x)*st.y;
  }
  #pragma unroll
  for (int o = 0; o < 16; ++o) {
    float acc = s_w0b[o];
    #pragma unroll
    for (int k = 0; k < 16; ++k) acc = fmaf(v[k], s_w0w[o*16+k], acc);
    uo[o] = acc + x1n[o];
  }
  float o0 = 0.f, o1 = 0.f, o2 = 0.f;
  for (int jj = 0; jj < 128; ++jj) {
    float t = s_fc1b[jj];
    #pragma unroll
    for (int k = 0; k < 16; ++k) t = fmaf(uo[k], s_fc1w[k*128 + jj], t);
    float s = __sinf(t);
    o0 = fmaf(s, s_fc2w[jj*3+0], o0);
    o1 = fmaf(s, s_fc2w[jj*3+1], o1);
    o2 = fmaf(s, s_fc2w[jj*3+2], o2);
  }
  out[((size_t)b*3 + 0)*NPIX + pix] = o0 + s_fc2b[0];
  out[((size_t)b*3 + 1)*NPIX + pix] = o1 + s_fc2b[1];
  out[((size_t)b*3 + 2)*NPIX + pix] = o2 + s_fc2b[2];
}

// ---------------------------------------------------------------------------
extern "C" void kernel_launch(void* const* d_in, const int* in_sizes, int n_in,
                              void* d_out, int out_size, void* d_ws, size_t ws_size,
                              hipStream_t stream) {
  const float*  x    = (const float*)d_in[0];
  const float*  fc0w = (const float*)d_in[1];
  const float*  fc0b = (const float*)d_in[2];
  const float2* p1   = (const float2*)d_in[3];
  const float2* p2   = (const float2*)d_in[4];
  const float2* res  = (const float2*)d_in[5];
  const float*  w0w  = (const float*)d_in[6];
  const float*  w0b  = (const float*)d_in[7];
  const float*  fc1w = (const float*)d_in[8];
  const float*  fc1b = (const float*)d_in[9];
  const float*  fc2w = (const float*)d_in[10];
  const float*  fc2b = (const float*)d_in[11];
  const float*  txv  = (const float*)d_in[12];
  const float*  tyv  = (const float*)d_in[13];
  float* out = (float*)d_out;

  // workspace layout (bytes); NEED == proven-safe 252,774,400
  const size_t OFF_A1   = 0;            // 4 MiB
  const size_t OFF_A2T  = 4194304;      // 4 MiB
  const size_t OFF_E1   = 8388608;      // 4 MiB
  const size_t OFF_E2   = 12582912;     // 4 MiB
  const size_t OFF_ST1  = 16777216;
  const size_t OFF_ST2  = 16778240;
  const size_t OFF_OUT2 = 16779264;     // 64 KiB
  const size_t OFF_MT   = 16844800;     // 1 MiB
  const size_t OFF_S    = 17893376;     // 32 MiB  (S)
  const size_t OFF_X1   = 51447808;     // 32 MiB  (Tt 4MiB early; X1 real later)
  const size_t OFF_A    = 85002240;     // 64 MiB  (spectrum ping / alpha)
  const size_t OFF_B    = 152111104;    // 64 MiB  (out1)
  const size_t OFF_G    = 219219968;    // 32 MiB  (U)
  const size_t NEED     = 252774400;
  if (ws_size < NEED) return;
  char* ws = (char*)d_ws;
  float2* A1  = (float2*)(ws + OFF_A1);
  float2* A2T = (float2*)(ws + OFF_A2T);
  float2* E1  = (float2*)(ws + OFF_E1);
  float2* E2  = (float2*)(ws + OFF_E2);
  float2* st1 = (float2*)(ws + OFF_ST1);
  float2* st2 = (float2*)(ws + OFF_ST2);
  float2* o2b = (float2*)(ws + OFF_OUT2);
  float2* Mt  = (float2*)(ws + OFF_MT);
  float2* Sb  = (float2*)(ws + OFF_S);
  float2* Tt  = (float2*)(ws + OFF_X1);   // dead before X1 is written
  float*  X1  = (float*)(ws + OFF_X1);
  float2* Ab  = (float2*)(ws + OFF_A);
  float2* Bb  = (float2*)(ws + OFF_B);
  float2* Ub  = (float2*)(ws + OFF_G);

  k_setup  <<<2048, 256, 0, stream>>>(p1, p2, txv, tyv, A1, A2T, E1, E2);
  k_T      <<<256, 256, 0, stream>>>(res, A1, Tt);
  k_stats_v<<<128, 256, 0, stream>>>(x, fc0w, fc0b, st1);
  // forward fft2: rows then columns (in place) -> alpha in Ab
  k_fft_v  <<<8192, 256, 0, stream>>>(x, fc0w, fc0b, st1, Ab);
  k_fft_col<<<2048, 256, 0, stream>>>(Ab, -1.f);                // Ab = alpha [b,i,o,x]
  // pole-residue spectral sums
  k_S      <<<2048, 256, 0, stream>>>(Ab, A2T, Sb);
  k_Mt     <<<2048, 256, 0, stream>>>(Sb, A1, Mt);
  k_out2   <<<32, 256, 0, stream>>>(Mt, res, o2b);
  // fused out1 (G built on the fly, per (o, k-pair) block)
  k_out1g  <<<2048, 256, 0, stream>>>(Ab, Tt, A2T, Bb);         // Bb = out1
  // inverse fft2: rows then columns, real output
  k_fft_c  <<<8192, 256, 0, stream>>>(Bb, Ab, +1.f, 1.f);       // ifft over x
  k_ifft_col_real<<<2048, 256, 0, stream>>>(Ab, X1, 1.0f/65536.0f); // X1 [img][h][w]
  // transient part added into x1pre
  k_U      <<<2048, 256, 0, stream>>>(o2b, E1, Ub);
  k_x2t    <<<4096, 256, 0, stream>>>(Ub, E2, X1);
  // second instance norm + heads
  k_stats_p<<<128, 256, 0, stream>>>(X1, st2);
  k_final  <<<2048, 256, 0, stream>>>(x, X1, st2, fc0w, fc0b,
                                      w0w, w0b, fc1w, fc1b, fc2w, fc2b, out);
}

// Round 5
// 774.654 us; speedup vs baseline: 1.1202x; 1.0067x over previous
//
#include <hip/hip_runtime.h>
#include <cstddef>

#define NPIX 65536
#define PI_F 3.14159265358979323846f

__device__ __forceinline__ void cacc(float2& acc, float2 a, float2 b) {
  acc.x = fmaf(a.x, b.x, fmaf(-a.y, b.y, acc.x));
  acc.y = fmaf(a.x, b.y, fmaf(a.y, b.x, acc.y));
}

// ---------------- 256-point radix-2 DIT FFT in LDS (one wave per line) -----
__device__ __forceinline__ void fft256(float* re, float* im, const float* twr,
                                       const float* twi, int lane) {
  #pragma unroll
  for (int s = 0; s < 8; ++s) {
    __syncthreads();
    const int half = 1 << s;
    #pragma unroll
    for (int r = 0; r < 2; ++r) {
      int m  = lane + 64*r;
      int t  = m & (half - 1);
      int g  = m >> s;
      int i0 = (g << (s+1)) + t;
      int i1 = i0 + half;
      int ti = t << (7 - s);
      float wr = twr[ti], wi = twi[ti];
      float br = re[i1], bi = im[i1];
      float vr = br*wr - bi*wi;
      float vi = br*wi + bi*wr;
      float ar = re[i0], ai = im[i0];
      re[i0] = ar + vr; im[i0] = ai + vi;
      re[i1] = ar - vr; im[i1] = ai - vi;
    }
  }
  __syncthreads();
}

// ---------------- setup: A1, A2T, E1, E2 ------------------------------------
__global__ __launch_bounds__(256) void k_setup(const float2* __restrict__ p1,
    const float2* __restrict__ p2, const float* __restrict__ txv,
    const float* __restrict__ tyv, float2* __restrict__ A1,
    float2* __restrict__ A2T, float2* __restrict__ E1, float2* __restrict__ E2) {
  int gid = blockIdx.x*256 + threadIdx.x;          // [0, 524288)
  int o = gid & 255, p = (gid>>8)&7, k = (gid>>11)&15, i = gid>>15;
  float ko = (o < 128) ? (float)o : (float)(o - 256);
  float dty = tyv[1] - tyv[0];
  float dtx = txv[1] - txv[0];
  const float TWO_PI = 6.283185307179586f;
  {
    float lam = TWO_PI * ko / (256.0f * dty);
    float2 pv = p1[(i*16+k)*8 + p];
    float xr = -pv.x, yi = lam - pv.y;
    float D = xr*xr + yi*yi;
    A1[((size_t)((i*16+k)*8 + p))*256 + o] = make_float2(xr/D, -yi/D);
    float tv = tyv[o];
    float m = expf(pv.x*tv);
    E1[((size_t)((i*16+k)*8 + p))*256 + o] = make_float2(m*cosf(pv.y*tv), m*sinf(pv.y*tv));
  }
  {
    float lam = TWO_PI * ko / (256.0f * dtx);
    float2 pv = p2[(i*16+k)*8 + p];
    float xr = -pv.x, yi = lam - pv.y;
    float D = xr*xr + yi*yi;
    A2T[((size_t)i*256 + o)*128 + k*8 + p] = make_float2(xr/D, -yi/D);
    float tv = txv[o];
    float m = expf(pv.x*tv);
    E2[((size_t)((i*16+k)*8 + p))*256 + o] = make_float2(m*cosf(pv.y*tv), m*sinf(pv.y*tv));
  }
}

// ---------------- T[ik][q][o] = sum_p res[ik][p][q] A1[ik][p][o] ------------
__global__ __launch_bounds__(256) void k_T(const float2* __restrict__ res,
    const float2* __restrict__ A1, float2* __restrict__ Tt) {
  int ik = blockIdx.x, tid = threadIdx.x;
  __shared__ float2 rbuf[64];
  __shared__ float2 a1[8][256];
  if (tid < 64) rbuf[tid] = res[(size_t)ik*64 + tid];
  for (int e = 0; e < 8; ++e) {
    int lin = tid + 256*e;
    int p = lin >> 8, o = lin & 255;
    a1[p][o] = A1[((size_t)ik*8 + p)*256 + o];
  }
  __syncthreads();
  int o = tid;
  #pragma unroll
  for (int q = 0; q < 8; ++q) {
    float2 acc = make_float2(0.f, 0.f);
    #pragma unroll
    for (int p = 0; p < 8; ++p) cacc(acc, rbuf[p*8+q], a1[p][o]);
    Tt[((size_t)ik*8 + q)*256 + o] = acc;
  }
}

// ---------------- stats of v (recomputed from x) ----------------------------
__global__ __launch_bounds__(256) void k_stats_v(const float* __restrict__ x,
    const float* __restrict__ fc0w, const float* __restrict__ fc0b,
    float2* __restrict__ stats) {
  int img = blockIdx.x, tid = threadIdx.x;
  int k = img & 15, b = img >> 4;
  float w0 = fc0w[k], w1 = fc0w[16+k], w2 = fc0w[32+k], w3 = fc0w[48+k], w4 = fc0w[64+k];
  float base = fc0b[k] + (tid*(1.0f/255.0f))*w4;
  const float* xb = x + (size_t)b*3*NPIX;
  float s = 0.f, s2 = 0.f;
  for (int it = 0; it < 256; ++it) {
    int p = it*256 + tid;
    float val = base + (it*(1.0f/255.0f))*w3 + xb[p]*w0 + xb[NPIX+p]*w1 + xb[2*NPIX+p]*w2;
    s += val; s2 += val*val;
  }
  __shared__ float rs[256], rq[256];
  rs[tid] = s; rq[tid] = s2;
  __syncthreads();
  for (int off = 128; off > 0; off >>= 1) {
    if (tid < off) { rs[tid] += rs[tid+off]; rq[tid] += rq[tid+off]; }
    __syncthreads();
  }
  if (tid == 0) {
    float mean = rs[0] * (1.0f/65536.0f);
    float var  = rq[0] * (1.0f/65536.0f) - mean*mean;
    stats[img] = make_float2(mean, rsqrtf(var + 1e-5f));
  }
}

// ---------------- stats of a real plane buffer ------------------------------
__global__ __launch_bounds__(256) void k_stats_p(const float* __restrict__ v,
    float2* __restrict__ stats) {
  int img = blockIdx.x, tid = threadIdx.x;
  const float* p = v + (size_t)img*NPIX;
  float s = 0.f, s2 = 0.f;
  for (int it = 0; it < 256; ++it) { float a = p[it*256 + tid]; s += a; s2 += a*a; }
  __shared__ float rs[256], rq[256];
  rs[tid] = s; rq[tid] = s2;
  __syncthreads();
  for (int off = 128; off > 0; off >>= 1) {
    if (tid < off) { rs[tid] += rs[tid+off]; rq[tid] += rq[tid+off]; }
    __syncthreads();
  }
  if (tid == 0) {
    float mean = rs[0] * (1.0f/65536.0f);
    float var  = rq[0] * (1.0f/65536.0f) - mean*mean;
    stats[img] = make_float2(mean, rsqrtf(var + 1e-5f));
  }
}

// ---------------- FFT over rows, input = normalized v recomputed from x -----
__global__ __launch_bounds__(256) void k_fft_v(const float* __restrict__ x,
    const float* __restrict__ fc0w, const float* __restrict__ fc0b,
    const float2* __restrict__ stats, float2* __restrict__ out) {
  __shared__ float sre[4][256], sim[4][256];
  __shared__ float twr[128], twi[128];
  int tid = threadIdx.x, lane = tid & 63, rowi = tid >> 6;
  int bid = blockIdx.x;                  // [0, 8192)
  int img = bid >> 6;
  int h   = (bid & 63)*4 + rowi;
  int k = img & 15, b = img >> 4;
  if (tid < 128) {
    float ang = (PI_F/128.0f)*tid;
    twr[tid] = cosf(ang); twi[tid] = -sinf(ang);
  }
  float2 st = stats[img];
  float w0 = fc0w[k], w1 = fc0w[16+k], w2 = fc0w[32+k], w3 = fc0w[48+k], w4 = fc0w[64+k];
  float bb = fc0b[k] + (h*(1.0f/255.0f))*w3;
  const float* xb = x + (size_t)b*3*NPIX + (size_t)h*256;
  float* re = sre[rowi]; float* im_ = sim[rowi];
  #pragma unroll
  for (int r = 0; r < 4; ++r) {
    int j = lane + 64*r;
    float val = bb + (j*(1.0f/255.0f))*w4 + xb[j]*w0 + xb[NPIX+j]*w1 + xb[2*NPIX+j]*w2;
    val = (val - st.x)*st.y;
    int bj = __brev((unsigned)j) >> 24;
    re[bj] = val; im_[bj] = 0.f;
  }
  fft256(re, im_, twr, twi, lane);
  float2* op = out + ((size_t)img*256 + h)*256;
  #pragma unroll
  for (int r = 0; r < 4; ++r) { int j = lane + 64*r; op[j] = make_float2(re[j], im_[j]); }
}

// ---------------- generic complex row FFT (dir=-1 fwd, +1 inv) --------------
__global__ __launch_bounds__(256) void k_fft_c(const float2* __restrict__ in,
    float2* __restrict__ out, float dir, float scale) {
  __shared__ float sre[4][256], sim[4][256];
  __shared__ float twr[128], twi[128];
  int tid = threadIdx.x, lane = tid & 63, rowi = tid >> 6;
  size_t row = (size_t)blockIdx.x*4 + rowi;      // [0, 32768)
  if (tid < 128) {
    float ang = (PI_F/128.0f)*tid;
    twr[tid] = cosf(ang); twi[tid] = dir*sinf(ang);
  }
  const float2* ip = in + row*256;
  float* re = sre[rowi]; float* im_ = sim[rowi];
  #pragma unroll
  for (int r = 0; r < 4; ++r) {
    int j = lane + 64*r;
    float2 v = ip[j];
    int bj = __brev((unsigned)j) >> 24;
    re[bj] = v.x; im_[bj] = v.y;
  }
  fft256(re, im_, twr, twi, lane);
  float2* op = out + row*256;
  #pragma unroll
  for (int r = 0; r < 4; ++r) { int j = lane + 64*r; op[j] = make_float2(re[j]*scale, im_[j]*scale); }
}

// ---- forward column FFT, writes o-major alphaR[o][img][x] ------------------
__global__ __launch_bounds__(256) void k_fft_colR(const float2* __restrict__ in,
    float2* __restrict__ outp) {
  __shared__ float tr[256][17], tim[256][17];
  __shared__ float twr[128], twi[128];
  int tid = threadIdx.x;
  int c = tid & 15, g = tid >> 4;               // column-in-tile, row-group
  int img = blockIdx.x >> 4;
  int c0  = (blockIdx.x & 15) * 16;
  if (tid < 128) {
    float ang = (PI_F/128.0f)*tid;
    twr[tid] = cosf(ang); twi[tid] = -sinf(ang);
  }
  const float2* base = in + (size_t)img*NPIX + c0;
  #pragma unroll
  for (int it = 0; it < 16; ++it) {
    int row = it*16 + g;
    float2 v = base[(size_t)row*256 + c];
    int br = __brev((unsigned)row) >> 24;
    tr[br][c] = v.x; tim[br][c] = v.y;
  }
  __syncthreads();
  for (int s = 0; s < 8; ++s) {
    int half = 1 << s;
    #pragma unroll
    for (int r = 0; r < 8; ++r) {
      int m  = g + 16*r;
      int t  = m & (half - 1);
      int grp = m >> s;
      int i0 = (grp << (s+1)) + t;
      int i1 = i0 + half;
      int twx = t << (7 - s);
      float wr = twr[twx], wi = twi[twx];
      float br = tr[i1][c], bi = tim[i1][c];
      float vr = br*wr - bi*wi, vi = br*wi + bi*wr;
      float ar = tr[i0][c], ai = tim[i0][c];
      tr[i0][c] = ar + vr; tim[i0][c] = ai + vi;
      tr[i1][c] = ar - vr; tim[i1][c] = ai - vi;
    }
    __syncthreads();
  }
  // o-major write: alphaR[(o*128 + img)*256 + x]
  #pragma unroll
  for (int it = 0; it < 16; ++it) {
    int row = it*16 + g;
    outp[((size_t)row*128 + img)*256 + c0 + c] = make_float2(tr[row][c], tim[row][c]);
  }
}

// ---------------- column inverse FFT, write real part to out ---------------
__global__ __launch_bounds__(256) void k_ifft_col_real(const float2* __restrict__ in,
    float* __restrict__ outp, float scale) {
  __shared__ float tr[256][17], tim[256][17];
  __shared__ float twr[128], twi[128];
  int tid = threadIdx.x;
  int c = tid & 15, g = tid >> 4;
  int img = blockIdx.x >> 4;
  int c0  = (blockIdx.x & 15) * 16;
  if (tid < 128) {
    float ang = (PI_F/128.0f)*tid;
    twr[tid] = cosf(ang); twi[tid] = sinf(ang);
  }
  const float2* base = in + (size_t)img*NPIX + c0;
  #pragma unroll
  for (int it = 0; it < 16; ++it) {
    int row = it*16 + g;
    float2 v = base[(size_t)row*256 + c];
    int br = __brev((unsigned)row) >> 24;
    tr[br][c] = v.x; tim[br][c] = v.y;
  }
  __syncthreads();
  for (int s = 0; s < 8; ++s) {
    int half = 1 << s;
    #pragma unroll
    for (int r = 0; r < 8; ++r) {
      int m  = g + 16*r;
      int t  = m & (half - 1);
      int grp = m >> s;
      int i0 = (grp << (s+1)) + t;
      int i1 = i0 + half;
      int twx = t << (7 - s);
      float wr = twr[twx], wi = twi[twx];
      float br = tr[i1][c], bi = tim[i1][c];
      float vr = br*wr - bi*wi, vi = br*wi + bi*wr;
      float ar = tr[i0][c], ai = tim[i0][c];
      tr[i0][c] = ar + vr; tim[i0][c] = ai + vi;
      tr[i1][c] = ar - vr; tim[i1][c] = ai - vi;
    }
    __syncthreads();
  }
  float* ob = outp + (size_t)img*NPIX + c0;
  #pragma unroll
  for (int it = 0; it < 16; ++it) {
    int row = it*16 + g;
    ob[(size_t)row*256 + c] = tr[row][c]*scale;
  }
}

// ---- S[n,i,o,(k,q)] = sum_x alphaR[o][ni][x] A2[i,k,q,x] -------------------
__global__ __launch_bounds__(256) void k_S(const float2* __restrict__ alphaR,
    const float2* __restrict__ A2T, float2* __restrict__ S) {
  __shared__ float2 al[16][256];
  int bid = blockIdx.x;               // (n*16+i)*16 + oblk
  int oblk = bid & 15, ni = bid >> 4;
  int i = ni & 15;
  int tid = threadIdx.x;
  for (int r = 0; r < 16; ++r)
    al[r][tid] = alphaR[((size_t)(oblk*16 + r)*128 + ni)*256 + tid];
  __syncthreads();
  int j = tid & 127, oh = tid >> 7;
  float2 acc[8];
  #pragma unroll
  for (int ol = 0; ol < 8; ++ol) acc[ol] = make_float2(0.f, 0.f);
  const float2* a2p = A2T + (size_t)i*32768 + j;
  float2 p0 = a2p[0], p1 = a2p[128], p2 = a2p[256], p3 = a2p[384];
  for (int xx = 0; xx < 256; xx += 4) {
    float2 a0 = p0, a1 = p1, a2v = p2, a3 = p3;
    int nx = xx + 4;
    if (nx < 256) {
      p0 = a2p[(size_t)nx*128];       p1 = a2p[(size_t)(nx+1)*128];
      p2 = a2p[(size_t)(nx+2)*128];   p3 = a2p[(size_t)(nx+3)*128];
    }
    #pragma unroll
    for (int ol = 0; ol < 8; ++ol) {
      cacc(acc[ol], al[oh*8+ol][xx],   a0);
      cacc(acc[ol], al[oh*8+ol][xx+1], a1);
      cacc(acc[ol], al[oh*8+ol][xx+2], a2v);
      cacc(acc[ol], al[oh*8+ol][xx+3], a3);
    }
  }
  #pragma unroll
  for (int ol = 0; ol < 8; ++ol) {
    int o = oblk*16 + oh*8 + ol;
    S[((size_t)ni*256 + o)*128 + j] = acc[ol];
  }
}

// ---------------- Mt[n,i,k,p,q] = sum_o S[n,i,o,(k,q)] A1[i,k,p,o] ----------
__global__ __launch_bounds__(256) void k_Mt(const float2* __restrict__ S,
    const float2* __restrict__ A1, float2* __restrict__ Mt) {
  __shared__ float2 sl[8][258];
  __shared__ float2 a1l[8][258];
  __shared__ float2 part[4][64];
  int bid = blockIdx.x;               // (n*16+i)*16 + k
  int k = bid & 15, ni = bid >> 4;
  int i = ni & 15;
  int ik = i*16 + k;
  int tid = threadIdx.x;
  for (int e = 0; e < 8; ++e) {
    int lin = tid + 256*e;            // 0..2047
    int o = lin >> 3, q = lin & 7;
    sl[q][o] = S[((size_t)ni*256 + o)*128 + k*8 + q];
  }
  for (int e = 0; e < 8; ++e) {
    int lin = tid + 256*e;
    int p = lin >> 8, o = lin & 255;
    a1l[p][o] = A1[((size_t)ik*8 + p)*256 + o];
  }
  __syncthreads();
  int oq = tid >> 6, pq = tid & 63, p = pq >> 3, q = pq & 7;
  float2 acc = make_float2(0.f, 0.f);
  int o0 = oq*64;
  for (int o = o0; o < o0 + 64; ++o) cacc(acc, sl[q][o], a1l[p][o]);
  part[oq][pq] = acc;
  __syncthreads();
  if (oq == 0) {
    float2 a = part[0][pq], b = part[1][pq], c = part[2][pq], d = part[3][pq];
    acc.x = a.x + b.x + c.x + d.x;
    acc.y = a.y + b.y + c.y + d.y;
    Mt[(size_t)bid*64 + pq] = acc;
  }
}

// ---------------- out2[n,k,p,q] = sum_i Mt[n,i,k,p,q] res[i,k,p,q] ----------
__global__ __launch_bounds__(256) void k_out2(const float2* __restrict__ Mt,
    const float2* __restrict__ res, float2* __restrict__ out2) {
  int gid = blockIdx.x*256 + threadIdx.x;   // [0, 8192)
  int pq = gid & 63, k = (gid >> 6) & 15, n = gid >> 10;
  float2 acc = make_float2(0.f, 0.f);
  for (int i = 0; i < 16; ++i)
    cacc(acc, Mt[((size_t)((n*16+i)*16 + k))*64 + pq], res[((size_t)(i*16+k))*64 + pq]);
  out2[((size_t)(n*16+k))*64 + pq] = acc;
}

// ---- fused out1: block = (o, k-pair); alphaR read contiguous per o ---------
// out1[b,k,o,x] = sum_i alphaR[o][b*16+i][x] * g_k[i](x),
// g_k[i](x) = sum_q T[ik,q,o] A2T[i,x,(k,q)]
__global__ __launch_bounds__(256) void k_out1g(const float2* __restrict__ alphaR,
    const float2* __restrict__ Tt, const float2* __restrict__ A2T,
    float2* __restrict__ out1) {
  // XCD-aware mapping: dispatch d -> xcd = d&7 owns o in [xcd*32, xcd*32+32)
  int d = blockIdx.x;                 // [0, 2048)
  int xcd = d & 7, idx = d >> 3;      // idx [0, 256)
  int o  = xcd*32 + (idx >> 3);
  int kh = idx & 7;                   // k pair: 2*kh, 2*kh+1
  int x = threadIdx.x;
  __shared__ float2 tl[2][128];       // T[i,q] at (2*kh+kk, o)
  {
    int t = threadIdx.x;              // 256 threads -> 256 entries
    int kk = t >> 7, rem = t & 127;
    int i = rem >> 3, q = rem & 7;
    tl[kk][rem] = Tt[((size_t)((i*16 + 2*kh + kk)*8 + q))*256 + o];
  }
  __syncthreads();
  float2 g0[16], g1[16];
  #pragma unroll
  for (int i = 0; i < 16; ++i) {
    const float2* a2 = &A2T[((size_t)i*256 + x)*128 + kh*16];
    float2 acc0 = make_float2(0.f, 0.f), acc1 = make_float2(0.f, 0.f);
    #pragma unroll
    for (int q = 0; q < 8; ++q) {
      cacc(acc0, tl[0][i*8+q], a2[q]);
      cacc(acc1, tl[1][i*8+q], a2[8+q]);
    }
    g0[i] = acc0; g1[i] = acc1;
  }
  const float2* arow = alphaR + (size_t)o*128*256 + x;   // rows bi, stride 256
  for (int b = 0; b < 8; ++b) {
    float2 acc0 = make_float2(0.f, 0.f), acc1 = make_float2(0.f, 0.f);
    #pragma unroll
    for (int i = 0; i < 16; ++i) {
      float2 al = arow[(size_t)(b*16 + i)*256];
      cacc(acc0, al, g0[i]);
      cacc(acc1, al, g1[i]);
    }
    out1[(((size_t)(b*16 + 2*kh + 0))*256 + o)*256 + x] = acc0;
    out1[(((size_t)(b*16 + 2*kh + 1))*256 + o)*256 + x] = acc1;
  }
}

// ---------------- U[n,j,kk,q,z] = sum_p out2[n,j,p,q] E1[j,kk,p,z] ----------
__global__ __launch_bounds__(256) void k_U(const float2* __restrict__ out2,
    const float2* __restrict__ E1, float2* __restrict__ U) {
  int bid = blockIdx.x;               // (n*16+j)*16 + kk
  int kk = bid & 15, nj = bid >> 4;
  int j = nj & 15;
  int z = threadIdx.x;
  __shared__ float2 o2[64];
  if (threadIdx.x < 64) o2[threadIdx.x] = out2[(size_t)nj*64 + threadIdx.x];
  __syncthreads();
  float2 e1[8];
  #pragma unroll
  for (int p = 0; p < 8; ++p) e1[p] = E1[(((size_t)(j*16+kk))*8 + p)*256 + z];
  #pragma unroll
  for (int q = 0; q < 8; ++q) {
    float2 acc = make_float2(0.f, 0.f);
    #pragma unroll
    for (int p = 0; p < 8; ++p) cacc(acc, o2[p*8+q], e1[p]);
    U[(((size_t)bid)*8 + q)*256 + z] = acc;
  }
}

// ---------------- x1pre += Re(sum_{j,q} U E2)/65536 -------------------------
__global__ __launch_bounds__(256) void k_x2t(const float2* __restrict__ U,
    const float2* __restrict__ E2, float* __restrict__ x1pre) {
  int bid = blockIdx.x;               // (n*16+kk)*32 + zb
  int zb = bid & 31, nk = bid >> 5;
  int kk = nk & 15, n = nk >> 4;
  int x = threadIdx.x;
  __shared__ float2 ul[1024];         // [j][q][z8]
  for (int e = 0; e < 4; ++e) {
    int lin = threadIdx.x + 256*e;
    int zz = lin & 7, q = (lin >> 3) & 7, j = lin >> 6;
    ul[lin] = U[((((size_t)(n*16+j))*16 + kk)*8 + q)*256 + zb*8 + zz];
  }
  __syncthreads();
  float acc[8] = {0.f,0.f,0.f,0.f,0.f,0.f,0.f,0.f};
  const float2* e2b = E2 + (size_t)kk*2048 + x;   // addr(j,q) = j*32768 + q*256
  float2 nxt = e2b[0];
  for (int jq = 0; jq < 128; ++jq) {
    float2 e2 = nxt;
    int njq = jq + 1;
    if (njq < 128) {
      int nj = njq >> 3, nq = njq & 7;
      nxt = e2b[(size_t)nj*32768 + (size_t)nq*256];
    }
    const float2* up = &ul[jq*8];
    #pragma unroll
    for (int zz = 0; zz < 8; ++zz) {
      float2 u = up[zz];
      acc[zz] = fmaf(u.x, e2.x, fmaf(-u.y, e2.y, acc[zz]));
    }
  }
  const float sc = 1.0f/65536.0f;
  #pragma unroll
  for (int zz = 0; zz < 8; ++zz) {
    size_t idx = (((size_t)nk)*256 + zb*8 + zz)*256 + x;
    x1pre[idx] += acc[zz]*sc;
  }
}

// ---------------- final: inorm(x1pre) + w0conv(v) -> fc1 -> sin -> fc2 ------
__global__ __launch_bounds__(256) void k_final(const float* __restrict__ x,
    const float* __restrict__ x1pre, const float2* __restrict__ stats2,
    const float* __restrict__ fc0w, const float* __restrict__ fc0b,
    const float* __restrict__ w0w, const float* __restrict__ w0b,
    const float* __restrict__ fc1w, const float* __restrict__ fc1b,
    const float* __restrict__ fc2w, const float* __restrict__ fc2b,
    float* __restrict__ out) {
  __shared__ float s_fc1w[2048], s_fc1b[128], s_fc2w[384], s_w0w[256], s_w0b[16], s_fc2b[3];
  int tid = threadIdx.x;
  for (int e = 0; e < 8; ++e) s_fc1w[tid + 256*e] = fc1w[tid + 256*e];
  if (tid < 128) s_fc1b[tid] = fc1b[tid];
  for (int e = 0; e < 2; ++e) { int q = tid + 256*e; if (q < 384) s_fc2w[q] = fc2w[q]; }
  s_w0w[tid] = w0w[tid];
  if (tid < 16) s_w0b[tid] = w0b[tid];
  if (tid < 3)  s_fc2b[tid] = fc2b[tid];
  __syncthreads();

  int bid = blockIdx.x;               // b*256 + h
  int hh = bid & 255, b = bid >> 8;
  int ww = tid;
  size_t pix = (size_t)hh*256 + ww;
  float xc0 = x[((size_t)b*3 + 0)*NPIX + pix];
  float xc1 = x[((size_t)b*3 + 1)*NPIX + pix];
  float xc2 = x[((size_t)b*3 + 2)*NPIX + pix];
  float gx = hh*(1.0f/255.0f), gy = ww*(1.0f/255.0f);
  float v[16], x1n[16], uo[16];
  #pragma unroll
  for (int k = 0; k < 16; ++k)
    v[k] = fc0b[k] + xc0*fc0w[k] + xc1*fc0w[16+k] + xc2*fc0w[32+k] + gx*fc0w[48+k] + gy*fc0w[64+k];
  #pragma unroll
  for (int k = 0; k < 16; ++k) {
    float2 st = stats2[b*16 + k];
    float xv = x1pre[((size_t)(b*16 + k))*NPIX + pix];
    x1n[k] = (xv - st.x)*st.y;
  }
  #pragma unroll
  for (int o = 0; o < 16; ++o) {
    float acc = s_w0b[o];
    #pragma unroll
    for (int k = 0; k < 16; ++k) acc = fmaf(v[k], s_w0w[o*16+k], acc);
    uo[o] = acc + x1n[o];
  }
  float o0 = 0.f, o1 = 0.f, o2 = 0.f;
  for (int jj = 0; jj < 128; ++jj) {
    float t = s_fc1b[jj];
    #pragma unroll
    for (int k = 0; k < 16; ++k) t = fmaf(uo[k], s_fc1w[k*128 + jj], t);
    float s = __sinf(t);
    o0 = fmaf(s, s_fc2w[jj*3+0], o0);
    o1 = fmaf(s, s_fc2w[jj*3+1], o1);
    o2 = fmaf(s, s_fc2w[jj*3+2], o2);
  }
  out[((size_t)b*3 + 0)*NPIX + pix] = o0 + s_fc2b[0];
  out[((size_t)b*3 + 1)*NPIX + pix] = o1 + s_fc2b[1];
  out[((size_t)b*3 + 2)*NPIX + pix] = o2 + s_fc2b[2];
}

// ---------------------------------------------------------------------------
extern "C" void kernel_launch(void* const* d_in, const int* in_sizes, int n_in,
                              void* d_out, int out_size, void* d_ws, size_t ws_size,
                              hipStream_t stream) {
  const float*  x    = (const float*)d_in[0];
  const float*  fc0w = (const float*)d_in[1];
  const float*  fc0b = (const float*)d_in[2];
  const float2* p1   = (const float2*)d_in[3];
  const float2* p2   = (const float2*)d_in[4];
  const float2* res  = (const float2*)d_in[5];
  const float*  w0w  = (const float*)d_in[6];
  const float*  w0b  = (const float*)d_in[7];
  const float*  fc1w = (const float*)d_in[8];
  const float*  fc1b = (const float*)d_in[9];
  const float*  fc2w = (const float*)d_in[10];
  const float*  fc2b = (const float*)d_in[11];
  const float*  txv  = (const float*)d_in[12];
  const float*  tyv  = (const float*)d_in[13];
  float* out = (float*)d_out;

  // workspace layout (bytes); NEED == proven-safe 252,774,400
  const size_t OFF_A1   = 0;            // 4 MiB
  const size_t OFF_A2T  = 4194304;      // 4 MiB
  const size_t OFF_E1   = 8388608;      // 4 MiB
  const size_t OFF_E2   = 12582912;     // 4 MiB
  const size_t OFF_ST1  = 16777216;
  const size_t OFF_ST2  = 16778240;
  const size_t OFF_OUT2 = 16779264;     // 64 KiB
  const size_t OFF_MT   = 16844800;     // 1 MiB
  const size_t OFF_S    = 17893376;     // 32 MiB  (S)
  const size_t OFF_X1   = 51447808;     // 32 MiB  (Tt 4MiB early; X1 real later)
  const size_t OFF_A    = 85002240;     // 64 MiB  (row-fft out; later out1)
  const size_t OFF_B    = 152111104;    // 64 MiB  (alphaR o-major; later spectra)
  const size_t OFF_G    = 219219968;    // 32 MiB  (U)
  const size_t NEED     = 252774400;
  if (ws_size < NEED) return;
  char* ws = (char*)d_ws;
  float2* A1  = (float2*)(ws + OFF_A1);
  float2* A2T = (float2*)(ws + OFF_A2T);
  float2* E1  = (float2*)(ws + OFF_E1);
  float2* E2  = (float2*)(ws + OFF_E2);
  float2* st1 = (float2*)(ws + OFF_ST1);
  float2* st2 = (float2*)(ws + OFF_ST2);
  float2* o2b = (float2*)(ws + OFF_OUT2);
  float2* Mt  = (float2*)(ws + OFF_MT);
  float2* Sb  = (float2*)(ws + OFF_S);
  float2* Tt  = (float2*)(ws + OFF_X1);   // dead before X1 is written
  float*  X1  = (float*)(ws + OFF_X1);
  float2* Ab  = (float2*)(ws + OFF_A);
  float2* Bb  = (float2*)(ws + OFF_B);
  float2* Ub  = (float2*)(ws + OFF_G);

  k_setup  <<<2048, 256, 0, stream>>>(p1, p2, txv, tyv, A1, A2T, E1, E2);
  k_T      <<<256, 256, 0, stream>>>(res, A1, Tt);
  k_stats_v<<<128, 256, 0, stream>>>(x, fc0w, fc0b, st1);
  // forward fft2: rows into Ab, columns into o-major alphaR (Bb)
  k_fft_v  <<<8192, 256, 0, stream>>>(x, fc0w, fc0b, st1, Ab);
  k_fft_colR<<<2048, 256, 0, stream>>>(Ab, Bb);                 // Bb = alphaR [o][bi][x]
  // pole-residue spectral sums
  k_S      <<<2048, 256, 0, stream>>>(Bb, A2T, Sb);
  k_Mt     <<<2048, 256, 0, stream>>>(Sb, A1, Mt);
  k_out2   <<<32, 256, 0, stream>>>(Mt, res, o2b);
  // fused out1 (G built on the fly, per (o, k-pair) block)
  k_out1g  <<<2048, 256, 0, stream>>>(Bb, Tt, A2T, Ab);         // Ab = out1 [img][o][x]
  // inverse fft2: rows then columns, real output
  k_fft_c  <<<8192, 256, 0, stream>>>(Ab, Bb, +1.f, 1.f);       // ifft over x
  k_ifft_col_real<<<2048, 256, 0, stream>>>(Bb, X1, 1.0f/65536.0f); // X1 [img][h][w]
  // transient part added into x1pre
  k_U      <<<2048, 256, 0, stream>>>(o2b, E1, Ub);
  k_x2t    <<<4096, 256, 0, stream>>>(Ub, E2, X1);
  // second instance norm + heads
  k_stats_p<<<128, 256, 0, stream>>>(X1, st2);
  k_final  <<<2048, 256, 0, stream>>>(x, X1, st2, fc0w, fc0b,
                                      w0w, w0b, fc1w, fc1b, fc2w, fc2b, out);
}

// Round 6
// 624.557 us; speedup vs baseline: 1.3894x; 1.2403x over previous
//
#include <hip/hip_runtime.h>
#include <cstddef>

#define NPIX 65536
#define PI_F 3.14159265358979323846f

__device__ __forceinline__ void cacc(float2& acc, float2 a, float2 b) {
  acc.x = fmaf(a.x, b.x, fmaf(-a.y, b.y, acc.x));
  acc.y = fmaf(a.x, b.y, fmaf(a.y, b.x, acc.y));
}

// ---------------- 256-point radix-2 DIT FFT in LDS (one wave per line) -----
__device__ __forceinline__ void fft256(float* re, float* im, const float* twr,
                                       const float* twi, int lane) {
  #pragma unroll
  for (int s = 0; s < 8; ++s) {
    __syncthreads();
    const int half = 1 << s;
    #pragma unroll
    for (int r = 0; r < 2; ++r) {
      int m  = lane + 64*r;
      int t  = m & (half - 1);
      int g  = m >> s;
      int i0 = (g << (s+1)) + t;
      int i1 = i0 + half;
      int ti = t << (7 - s);
      float wr = twr[ti], wi = twi[ti];
      float br = re[i1], bi = im[i1];
      float vr = br*wr - bi*wi;
      float vi = br*wi + bi*wr;
      float ar = re[i0], ai = im[i0];
      re[i0] = ar + vr; im[i0] = ai + vi;
      re[i1] = ar - vr; im[i1] = ai - vi;
    }
  }
  __syncthreads();
}

// ---------------- setup: A1, A2T, A2L, E1, E2 -------------------------------
__global__ __launch_bounds__(256) void k_setup(const float2* __restrict__ p1,
    const float2* __restrict__ p2, const float* __restrict__ txv,
    const float* __restrict__ tyv, float2* __restrict__ A1,
    float2* __restrict__ A2T, float2* __restrict__ A2L,
    float2* __restrict__ E1, float2* __restrict__ E2) {
  int gid = blockIdx.x*256 + threadIdx.x;          // [0, 524288)
  int o = gid & 255, p = (gid>>8)&7, k = (gid>>11)&15, i = gid>>15;
  float ko = (o < 128) ? (float)o : (float)(o - 256);
  float dty = tyv[1] - tyv[0];
  float dtx = txv[1] - txv[0];
  const float TWO_PI = 6.283185307179586f;
  {
    float lam = TWO_PI * ko / (256.0f * dty);
    float2 pv = p1[(i*16+k)*8 + p];
    float xr = -pv.x, yi = lam - pv.y;
    float D = xr*xr + yi*yi;
    A1[((size_t)((i*16+k)*8 + p))*256 + o] = make_float2(xr/D, -yi/D);
    float tv = tyv[o];
    float m = expf(pv.x*tv);
    E1[((size_t)((i*16+k)*8 + p))*256 + o] = make_float2(m*cosf(pv.y*tv), m*sinf(pv.y*tv));
  }
  {
    float lam = TWO_PI * ko / (256.0f * dtx);
    float2 pv = p2[(i*16+k)*8 + p];
    float xr = -pv.x, yi = lam - pv.y;
    float D = xr*xr + yi*yi;
    float2 val = make_float2(xr/D, -yi/D);
    A2T[((size_t)i*256 + o)*128 + k*8 + p] = val;
    A2L[((size_t)((i*16+k)*8 + p))*256 + o] = val;
    float tv = txv[o];
    float m = expf(pv.x*tv);
    E2[((size_t)((i*16+k)*8 + p))*256 + o] = make_float2(m*cosf(pv.y*tv), m*sinf(pv.y*tv));
  }
}

// ---------------- T[ik][q][o] = sum_p res[ik][p][q] A1[ik][p][o] ------------
__global__ __launch_bounds__(256) void k_T(const float2* __restrict__ res,
    const float2* __restrict__ A1, float2* __restrict__ Tt) {
  int ik = blockIdx.x, tid = threadIdx.x;
  __shared__ float2 rbuf[64];
  __shared__ float2 a1[8][256];
  if (tid < 64) rbuf[tid] = res[(size_t)ik*64 + tid];
  for (int e = 0; e < 8; ++e) {
    int lin = tid + 256*e;
    int p = lin >> 8, o = lin & 255;
    a1[p][o] = A1[((size_t)ik*8 + p)*256 + o];
  }
  __syncthreads();
  int o = tid;
  #pragma unroll
  for (int q = 0; q < 8; ++q) {
    float2 acc = make_float2(0.f, 0.f);
    #pragma unroll
    for (int p = 0; p < 8; ++p) cacc(acc, rbuf[p*8+q], a1[p][o]);
    Tt[((size_t)ik*8 + q)*256 + o] = acc;
  }
}

// ---------------- stats of v (recomputed from x) ----------------------------
__global__ __launch_bounds__(256) void k_stats_v(const float* __restrict__ x,
    const float* __restrict__ fc0w, const float* __restrict__ fc0b,
    float2* __restrict__ stats) {
  int img = blockIdx.x, tid = threadIdx.x;
  int k = img & 15, b = img >> 4;
  float w0 = fc0w[k], w1 = fc0w[16+k], w2 = fc0w[32+k], w3 = fc0w[48+k], w4 = fc0w[64+k];
  float base = fc0b[k] + (tid*(1.0f/255.0f))*w4;
  const float* xb = x + (size_t)b*3*NPIX;
  float s = 0.f, s2 = 0.f;
  for (int it = 0; it < 256; ++it) {
    int p = it*256 + tid;
    float val = base + (it*(1.0f/255.0f))*w3 + xb[p]*w0 + xb[NPIX+p]*w1 + xb[2*NPIX+p]*w2;
    s += val; s2 += val*val;
  }
  __shared__ float rs[256], rq[256];
  rs[tid] = s; rq[tid] = s2;
  __syncthreads();
  for (int off = 128; off > 0; off >>= 1) {
    if (tid < off) { rs[tid] += rs[tid+off]; rq[tid] += rq[tid+off]; }
    __syncthreads();
  }
  if (tid == 0) {
    float mean = rs[0] * (1.0f/65536.0f);
    float var  = rq[0] * (1.0f/65536.0f) - mean*mean;
    stats[img] = make_float2(mean, rsqrtf(var + 1e-5f));
  }
}

// ---------------- stats of a real plane buffer ------------------------------
__global__ __launch_bounds__(256) void k_stats_p(const float* __restrict__ v,
    float2* __restrict__ stats) {
  int img = blockIdx.x, tid = threadIdx.x;
  const float* p = v + (size_t)img*NPIX;
  float s = 0.f, s2 = 0.f;
  for (int it = 0; it < 256; ++it) { float a = p[it*256 + tid]; s += a; s2 += a*a; }
  __shared__ float rs[256], rq[256];
  rs[tid] = s; rq[tid] = s2;
  __syncthreads();
  for (int off = 128; off > 0; off >>= 1) {
    if (tid < off) { rs[tid] += rs[tid+off]; rq[tid] += rq[tid+off]; }
    __syncthreads();
  }
  if (tid == 0) {
    float mean = rs[0] * (1.0f/65536.0f);
    float var  = rq[0] * (1.0f/65536.0f) - mean*mean;
    stats[img] = make_float2(mean, rsqrtf(var + 1e-5f));
  }
}

// ---------------- FFT over rows, input = normalized v recomputed from x -----
__global__ __launch_bounds__(256) void k_fft_v(const float* __restrict__ x,
    const float* __restrict__ fc0w, const float* __restrict__ fc0b,
    const float2* __restrict__ stats, float2* __restrict__ out) {
  __shared__ float sre[4][256], sim[4][256];
  __shared__ float twr[128], twi[128];
  int tid = threadIdx.x, lane = tid & 63, rowi = tid >> 6;
  int bid = blockIdx.x;                  // [0, 8192)
  int img = bid >> 6;
  int h   = (bid & 63)*4 + rowi;
  int k = img & 15, b = img >> 4;
  if (tid < 128) {
    float ang = (PI_F/128.0f)*tid;
    twr[tid] = cosf(ang); twi[tid] = -sinf(ang);
  }
  float2 st = stats[img];
  float w0 = fc0w[k], w1 = fc0w[16+k], w2 = fc0w[32+k], w3 = fc0w[48+k], w4 = fc0w[64+k];
  float bb = fc0b[k] + (h*(1.0f/255.0f))*w3;
  const float* xb = x + (size_t)b*3*NPIX + (size_t)h*256;
  float* re = sre[rowi]; float* im_ = sim[rowi];
  #pragma unroll
  for (int r = 0; r < 4; ++r) {
    int j = lane + 64*r;
    float val = bb + (j*(1.0f/255.0f))*w4 + xb[j]*w0 + xb[NPIX+j]*w1 + xb[2*NPIX+j]*w2;
    val = (val - st.x)*st.y;
    int bj = __brev((unsigned)j) >> 24;
    re[bj] = val; im_[bj] = 0.f;
  }
  fft256(re, im_, twr, twi, lane);
  float2* op = out + ((size_t)img*256 + h)*256;
  #pragma unroll
  for (int r = 0; r < 4; ++r) { int j = lane + 64*r; op[j] = make_float2(re[j], im_[j]); }
}

// ---------------- generic complex row FFT (dir=-1 fwd, +1 inv) --------------
__global__ __launch_bounds__(256) void k_fft_c(const float2* __restrict__ in,
    float2* __restrict__ out, float dir, float scale) {
  __shared__ float sre[4][256], sim[4][256];
  __shared__ float twr[128], twi[128];
  int tid = threadIdx.x, lane = tid & 63, rowi = tid >> 6;
  size_t row = (size_t)blockIdx.x*4 + rowi;      // [0, 32768)
  if (tid < 128) {
    float ang = (PI_F/128.0f)*tid;
    twr[tid] = cosf(ang); twi[tid] = dir*sinf(ang);
  }
  const float2* ip = in + row*256;
  float* re = sre[rowi]; float* im_ = sim[rowi];
  #pragma unroll
  for (int r = 0; r < 4; ++r) {
    int j = lane + 64*r;
    float2 v = ip[j];
    int bj = __brev((unsigned)j) >> 24;
    re[bj] = v.x; im_[bj] = v.y;
  }
  fft256(re, im_, twr, twi, lane);
  float2* op = out + row*256;
  #pragma unroll
  for (int r = 0; r < 4; ++r) { int j = lane + 64*r; op[j] = make_float2(re[j]*scale, im_[j]*scale); }
}

// ---- forward column FFT, writes o-major alphaR[o][img][x] ------------------
__global__ __launch_bounds__(256) void k_fft_colR(const float2* __restrict__ in,
    float2* __restrict__ outp) {
  __shared__ float tr[256][17], tim[256][17];
  __shared__ float twr[128], twi[128];
  int tid = threadIdx.x;
  int c = tid & 15, g = tid >> 4;               // column-in-tile, row-group
  int img = blockIdx.x >> 4;
  int c0  = (blockIdx.x & 15) * 16;
  if (tid < 128) {
    float ang = (PI_F/128.0f)*tid;
    twr[tid] = cosf(ang); twi[tid] = -sinf(ang);
  }
  const float2* base = in + (size_t)img*NPIX + c0;
  #pragma unroll
  for (int it = 0; it < 16; ++it) {
    int row = it*16 + g;
    float2 v = base[(size_t)row*256 + c];
    int br = __brev((unsigned)row) >> 24;
    tr[br][c] = v.x; tim[br][c] = v.y;
  }
  __syncthreads();
  for (int s = 0; s < 8; ++s) {
    int half = 1 << s;
    #pragma unroll
    for (int r = 0; r < 8; ++r) {
      int m  = g + 16*r;
      int t  = m & (half - 1);
      int grp = m >> s;
      int i0 = (grp << (s+1)) + t;
      int i1 = i0 + half;
      int twx = t << (7 - s);
      float wr = twr[twx], wi = twi[twx];
      float br = tr[i1][c], bi = tim[i1][c];
      float vr = br*wr - bi*wi, vi = br*wi + bi*wr;
      float ar = tr[i0][c], ai = tim[i0][c];
      tr[i0][c] = ar + vr; tim[i0][c] = ai + vi;
      tr[i1][c] = ar - vr; tim[i1][c] = ai - vi;
    }
    __syncthreads();
  }
  // o-major write: alphaR[(o*128 + img)*256 + x]
  #pragma unroll
  for (int it = 0; it < 16; ++it) {
    int row = it*16 + g;
    outp[((size_t)row*128 + img)*256 + c0 + c] = make_float2(tr[row][c], tim[row][c]);
  }
}

// ---------------- column inverse FFT, write real part to out ---------------
__global__ __launch_bounds__(256) void k_ifft_col_real(const float2* __restrict__ in,
    float* __restrict__ outp, float scale) {
  __shared__ float tr[256][17], tim[256][17];
  __shared__ float twr[128], twi[128];
  int tid = threadIdx.x;
  int c = tid & 15, g = tid >> 4;
  int img = blockIdx.x >> 4;
  int c0  = (blockIdx.x & 15) * 16;
  if (tid < 128) {
    float ang = (PI_F/128.0f)*tid;
    twr[tid] = cosf(ang); twi[tid] = sinf(ang);
  }
  const float2* base = in + (size_t)img*NPIX + c0;
  #pragma unroll
  for (int it = 0; it < 16; ++it) {
    int row = it*16 + g;
    float2 v = base[(size_t)row*256 + c];
    int br = __brev((unsigned)row) >> 24;
    tr[br][c] = v.x; tim[br][c] = v.y;
  }
  __syncthreads();
  for (int s = 0; s < 8; ++s) {
    int half = 1 << s;
    #pragma unroll
    for (int r = 0; r < 8; ++r) {
      int m  = g + 16*r;
      int t  = m & (half - 1);
      int grp = m >> s;
      int i0 = (grp << (s+1)) + t;
      int i1 = i0 + half;
      int twx = t << (7 - s);
      float wr = twr[twx], wi = twi[twx];
      float br = tr[i1][c], bi = tim[i1][c];
      float vr = br*wr - bi*wi, vi = br*wi + bi*wr;
      float ar = tr[i0][c], ai = tim[i0][c];
      tr[i0][c] = ar + vr; tim[i0][c] = ai + vi;
      tr[i1][c] = ar - vr; tim[i1][c] = ai - vi;
    }
    __syncthreads();
  }
  float* ob = outp + (size_t)img*NPIX + c0;
  #pragma unroll
  for (int it = 0; it < 16; ++it) {
    int row = it*16 + g;
    ob[(size_t)row*256 + c] = tr[row][c]*scale;
  }
}

// ---- S[n,i,o,(k,q)] = sum_x alphaR[o][ni][x] A2[i,k,q,x] -------------------
__global__ __launch_bounds__(256) void k_S(const float2* __restrict__ alphaR,
    const float2* __restrict__ A2T, float2* __restrict__ S) {
  __shared__ float2 al[16][256];
  int bid = blockIdx.x;               // (n*16+i)*16 + oblk
  int oblk = bid & 15, ni = bid >> 4;
  int i = ni & 15;
  int tid = threadIdx.x;
  for (int r = 0; r < 16; ++r)
    al[r][tid] = alphaR[((size_t)(oblk*16 + r)*128 + ni)*256 + tid];
  __syncthreads();
  int j = tid & 127, oh = tid >> 7;
  float2 acc[8];
  #pragma unroll
  for (int ol = 0; ol < 8; ++ol) acc[ol] = make_float2(0.f, 0.f);
  const float2* a2p = A2T + (size_t)i*32768 + j;
  float2 p0 = a2p[0], p1 = a2p[128], p2 = a2p[256], p3 = a2p[384];
  for (int xx = 0; xx < 256; xx += 4) {
    float2 a0 = p0, a1 = p1, a2v = p2, a3 = p3;
    int nx = xx + 4;
    if (nx < 256) {
      p0 = a2p[(size_t)nx*128];       p1 = a2p[(size_t)(nx+1)*128];
      p2 = a2p[(size_t)(nx+2)*128];   p3 = a2p[(size_t)(nx+3)*128];
    }
    #pragma unroll
    for (int ol = 0; ol < 8; ++ol) {
      cacc(acc[ol], al[oh*8+ol][xx],   a0);
      cacc(acc[ol], al[oh*8+ol][xx+1], a1);
      cacc(acc[ol], al[oh*8+ol][xx+2], a2v);
      cacc(acc[ol], al[oh*8+ol][xx+3], a3);
    }
  }
  #pragma unroll
  for (int ol = 0; ol < 8; ++ol) {
    int o = oblk*16 + oh*8 + ol;
    S[((size_t)ni*256 + o)*128 + j] = acc[ol];
  }
}

// ---------------- Mt[n,i,k,p,q] = sum_o S[n,i,o,(k,q)] A1[i,k,p,o] ----------
__global__ __launch_bounds__(256) void k_Mt(const float2* __restrict__ S,
    const float2* __restrict__ A1, float2* __restrict__ Mt) {
  __shared__ float2 sl[8][258];
  __shared__ float2 a1l[8][258];
  __shared__ float2 part[4][64];
  int bid = blockIdx.x;               // (n*16+i)*16 + k
  int k = bid & 15, ni = bid >> 4;
  int i = ni & 15;
  int ik = i*16 + k;
  int tid = threadIdx.x;
  for (int e = 0; e < 8; ++e) {
    int lin = tid + 256*e;            // 0..2047
    int o = lin >> 3, q = lin & 7;
    sl[q][o] = S[((size_t)ni*256 + o)*128 + k*8 + q];
  }
  for (int e = 0; e < 8; ++e) {
    int lin = tid + 256*e;
    int p = lin >> 8, o = lin & 255;
    a1l[p][o] = A1[((size_t)ik*8 + p)*256 + o];
  }
  __syncthreads();
  int oq = tid >> 6, pq = tid & 63, p = pq >> 3, q = pq & 7;
  float2 acc = make_float2(0.f, 0.f);
  int o0 = oq*64;
  for (int o = o0; o < o0 + 64; ++o) cacc(acc, sl[q][o], a1l[p][o]);
  part[oq][pq] = acc;
  __syncthreads();
  if (oq == 0) {
    float2 a = part[0][pq], b = part[1][pq], c = part[2][pq], d = part[3][pq];
    acc.x = a.x + b.x + c.x + d.x;
    acc.y = a.y + b.y + c.y + d.y;
    Mt[(size_t)bid*64 + pq] = acc;
  }
}

// ---------------- out2[n,k,p,q] = sum_i Mt[n,i,k,p,q] res[i,k,p,q] ----------
__global__ __launch_bounds__(256) void k_out2(const float2* __restrict__ Mt,
    const float2* __restrict__ res, float2* __restrict__ out2) {
  int gid = blockIdx.x*256 + threadIdx.x;   // [0, 8192)
  int pq = gid & 63, k = (gid >> 6) & 15, n = gid >> 10;
  float2 acc = make_float2(0.f, 0.f);
  for (int i = 0; i < 16; ++i)
    cacc(acc, Mt[((size_t)((n*16+i)*16 + k))*64 + pq], res[((size_t)(i*16+k))*64 + pq]);
  out2[((size_t)(n*16+k))*64 + pq] = acc;
}

// ---- fused out1: block = (o, k-pair); A2L reads lane-contiguous ------------
// out1[b,k,o,x] = sum_i alphaR[o][b*16+i][x] * g_k[i](x),
// g_k[i](x) = sum_q T[ik,q,o] A2L[ik,q,x]
__global__ __launch_bounds__(256) void k_out1g(const float2* __restrict__ alphaR,
    const float2* __restrict__ Tt, const float2* __restrict__ A2L,
    float2* __restrict__ out1) {
  // XCD-aware mapping: dispatch d -> xcd = d&7 owns o in [xcd*32, xcd*32+32)
  int d = blockIdx.x;                 // [0, 2048)
  int xcd = d & 7, idx = d >> 3;      // idx [0, 256)
  int o  = xcd*32 + (idx >> 3);
  int kh = idx & 7;                   // k pair: 2*kh, 2*kh+1
  int x = threadIdx.x;
  __shared__ float2 tl[2][128];       // T[i,q] at (2*kh+kk, o)
  {
    int t = threadIdx.x;              // 256 threads -> 256 entries
    int kk = t >> 7, rem = t & 127;
    int i = rem >> 3, q = rem & 7;
    tl[kk][rem] = Tt[((size_t)((i*16 + 2*kh + kk)*8 + q))*256 + o];
  }
  __syncthreads();
  float2 g0[16], g1[16];
  #pragma unroll
  for (int i = 0; i < 16; ++i) {
    const float2* a2k0 = &A2L[((size_t)((i*16 + 2*kh + 0)*8))*256 + x];
    const float2* a2k1 = &A2L[((size_t)((i*16 + 2*kh + 1)*8))*256 + x];
    float2 acc0 = make_float2(0.f, 0.f), acc1 = make_float2(0.f, 0.f);
    #pragma unroll
    for (int q = 0; q < 8; ++q) {
      cacc(acc0, tl[0][i*8+q], a2k0[(size_t)q*256]);
      cacc(acc1, tl[1][i*8+q], a2k1[(size_t)q*256]);
    }
    g0[i] = acc0; g1[i] = acc1;
  }
  const float2* arow = alphaR + (size_t)o*128*256 + x;   // rows bi, stride 256
  for (int b = 0; b < 8; ++b) {
    float2 acc0 = make_float2(0.f, 0.f), acc1 = make_float2(0.f, 0.f);
    #pragma unroll
    for (int i = 0; i < 16; ++i) {
      float2 al = arow[(size_t)(b*16 + i)*256];
      cacc(acc0, al, g0[i]);
      cacc(acc1, al, g1[i]);
    }
    out1[(((size_t)(b*16 + 2*kh + 0))*256 + o)*256 + x] = acc0;
    out1[(((size_t)(b*16 + 2*kh + 1))*256 + o)*256 + x] = acc1;
  }
}

// ---- x1pre += Re(sum_{j,q} U E2)/65536, U computed on the fly --------------
// U[j,q,zz] = sum_p out2[n,j,p,q] E1[j,kk,p, zb*8+zz]
__global__ __launch_bounds__(256) void k_x2t(const float2* __restrict__ out2,
    const float2* __restrict__ E1, const float2* __restrict__ E2,
    float* __restrict__ x1pre) {
  int bid = blockIdx.x;               // (n*16+kk)*32 + zb
  int zb = bid & 31, nk = bid >> 5;
  int kk = nk & 15, n = nk >> 4;
  int x = threadIdx.x;
  __shared__ float2 o2[1024];         // [j][p][q]
  __shared__ float2 e1l[1024];        // [j][p][zz]
  __shared__ float2 ul[1024];         // [j][q][zz]
  for (int e = 0; e < 4; ++e) {
    int lin = threadIdx.x + 256*e;    // j*64 + pq
    int j = lin >> 6, pq = lin & 63;
    o2[lin] = out2[((size_t)(n*16 + j))*64 + pq];
  }
  for (int e = 0; e < 4; ++e) {
    int lin = threadIdx.x + 256*e;    // j*64 + p*8 + zz
    int j = lin >> 6, p = (lin >> 3) & 7, zz = lin & 7;
    e1l[lin] = E1[(((size_t)(j*16 + kk))*8 + p)*256 + zb*8 + zz];
  }
  __syncthreads();
  for (int e = 0; e < 4; ++e) {
    int lin = threadIdx.x + 256*e;    // j*64 + q*8 + zz
    int j = lin >> 6, q = (lin >> 3) & 7, zz = lin & 7;
    float2 acc = make_float2(0.f, 0.f);
    #pragma unroll
    for (int p = 0; p < 8; ++p) cacc(acc, o2[j*64 + p*8 + q], e1l[j*64 + p*8 + zz]);
    ul[lin] = acc;
  }
  __syncthreads();
  float acc[8] = {0.f,0.f,0.f,0.f,0.f,0.f,0.f,0.f};
  const float2* e2b = E2 + (size_t)kk*2048 + x;   // addr(j,q) = j*32768 + q*256
  float2 nxt = e2b[0];
  for (int jq = 0; jq < 128; ++jq) {
    float2 e2 = nxt;
    int njq = jq + 1;
    if (njq < 128) {
      int nj = njq >> 3, nq = njq & 7;
      nxt = e2b[(size_t)nj*32768 + (size_t)nq*256];
    }
    const float2* up = &ul[jq*8];
    #pragma unroll
    for (int zz = 0; zz < 8; ++zz) {
      float2 u = up[zz];
      acc[zz] = fmaf(u.x, e2.x, fmaf(-u.y, e2.y, acc[zz]));
    }
  }
  const float sc = 1.0f/65536.0f;
  #pragma unroll
  for (int zz = 0; zz < 8; ++zz) {
    size_t idx = (((size_t)nk)*256 + zb*8 + zz)*256 + x;
    x1pre[idx] += acc[zz]*sc;
  }
}

// ---------------- final: inorm(x1pre) + w0conv(v) -> fc1 -> sin -> fc2 ------
__global__ __launch_bounds__(256) void k_final(const float* __restrict__ x,
    const float* __restrict__ x1pre, const float2* __restrict__ stats2,
    const float* __restrict__ fc0w, const float* __restrict__ fc0b,
    const float* __restrict__ w0w, const float* __restrict__ w0b,
    const float* __restrict__ fc1w, const float* __restrict__ fc1b,
    const float* __restrict__ fc2w, const float* __restrict__ fc2b,
    float* __restrict__ out) {
  __shared__ float s_fc1w[2048], s_fc1b[128], s_fc2w[384], s_w0w[256], s_w0b[16], s_fc2b[3];
  int tid = threadIdx.x;
  for (int e = 0; e < 8; ++e) s_fc1w[tid + 256*e] = fc1w[tid + 256*e];
  if (tid < 128) s_fc1b[tid] = fc1b[tid];
  for (int e = 0; e < 2; ++e) { int q = tid + 256*e; if (q < 384) s_fc2w[q] = fc2w[q]; }
  s_w0w[tid] = w0w[tid];
  if (tid < 16) s_w0b[tid] = w0b[tid];
  if (tid < 3)  s_fc2b[tid] = fc2b[tid];
  __syncthreads();

  int bid = blockIdx.x;               // b*256 + h
  int hh = bid & 255, b = bid >> 8;
  int ww = tid;
  size_t pix = (size_t)hh*256 + ww;
  float xc0 = x[((size_t)b*3 + 0)*NPIX + pix];
  float xc1 = x[((size_t)b*3 + 1)*NPIX + pix];
  float xc2 = x[((size_t)b*3 + 2)*NPIX + pix];
  float gx = hh*(1.0f/255.0f), gy = ww*(1.0f/255.0f);
  float v[16], x1n[16], uo[16];
  #pragma unroll
  for (int k = 0; k < 16; ++k)
    v[k] = fc0b[k] + xc0*fc0w[k] + xc1*fc0w[16+k] + xc2*fc0w[32+k] + gx*fc0w[48+k] + gy*fc0w[64+k];
  #pragma unroll
  for (int k = 0; k < 16; ++k) {
    float2 st = stats2[b*16 + k];
    float xv = x1pre[((size_t)(b*16 + k))*NPIX + pix];
    x1n[k] = (xv - st.x)*st.y;
  }
  #pragma unroll
  for (int o = 0; o < 16; ++o) {
    float acc = s_w0b[o];
    #pragma unroll
    for (int k = 0; k < 16; ++k) acc = fmaf(v[k], s_w0w[o*16+k], acc);
    uo[o] = acc + x1n[o];
  }
  float o0 = 0.f, o1 = 0.f, o2 = 0.f;
  for (int jj = 0; jj < 128; ++jj) {
    float t = s_fc1b[jj];
    #pragma unroll
    for (int k = 0; k < 16; ++k) t = fmaf(uo[k], s_fc1w[k*128 + jj], t);
    float s = __sinf(t);
    o0 = fmaf(s, s_fc2w[jj*3+0], o0);
    o1 = fmaf(s, s_fc2w[jj*3+1], o1);
    o2 = fmaf(s, s_fc2w[jj*3+2], o2);
  }
  out[((size_t)b*3 + 0)*NPIX + pix] = o0 + s_fc2b[0];
  out[((size_t)b*3 + 1)*NPIX + pix] = o1 + s_fc2b[1];
  out[((size_t)b*3 + 2)*NPIX + pix] = o2 + s_fc2b[2];
}

// ---------------------------------------------------------------------------
extern "C" void kernel_launch(void* const* d_in, const int* in_sizes, int n_in,
                              void* d_out, int out_size, void* d_ws, size_t ws_size,
                              hipStream_t stream) {
  const float*  x    = (const float*)d_in[0];
  const float*  fc0w = (const float*)d_in[1];
  const float*  fc0b = (const float*)d_in[2];
  const float2* p1   = (const float2*)d_in[3];
  const float2* p2   = (const float2*)d_in[4];
  const float2* res  = (const float2*)d_in[5];
  const float*  w0w  = (const float*)d_in[6];
  const float*  w0b  = (const float*)d_in[7];
  const float*  fc1w = (const float*)d_in[8];
  const float*  fc1b = (const float*)d_in[9];
  const float*  fc2w = (const float*)d_in[10];
  const float*  fc2b = (const float*)d_in[11];
  const float*  txv  = (const float*)d_in[12];
  const float*  tyv  = (const float*)d_in[13];
  float* out = (float*)d_out;

  // workspace layout (bytes); NEED == proven-safe 252,774,400
  const size_t OFF_A1   = 0;            // 4 MiB
  const size_t OFF_A2T  = 4194304;      // 4 MiB
  const size_t OFF_E1   = 8388608;      // 4 MiB
  const size_t OFF_E2   = 12582912;     // 4 MiB
  const size_t OFF_ST1  = 16777216;
  const size_t OFF_ST2  = 16778240;
  const size_t OFF_OUT2 = 16779264;     // 64 KiB
  const size_t OFF_MT   = 16844800;     // 1 MiB
  const size_t OFF_S    = 17893376;     // 32 MiB  (S)
  const size_t OFF_X1   = 51447808;     // 32 MiB  (Tt 4MiB early; X1 real later)
  const size_t OFF_A    = 85002240;     // 64 MiB  (row-fft out; later out1)
  const size_t OFF_B    = 152111104;    // 64 MiB  (alphaR o-major; later spectra)
  const size_t OFF_G    = 219219968;    // 32 MiB  (A2L 4 MiB)
  const size_t NEED     = 252774400;
  if (ws_size < NEED) return;
  char* ws = (char*)d_ws;
  float2* A1  = (float2*)(ws + OFF_A1);
  float2* A2T = (float2*)(ws + OFF_A2T);
  float2* E1  = (float2*)(ws + OFF_E1);
  float2* E2  = (float2*)(ws + OFF_E2);
  float2* st1 = (float2*)(ws + OFF_ST1);
  float2* st2 = (float2*)(ws + OFF_ST2);
  float2* o2b = (float2*)(ws + OFF_OUT2);
  float2* Mt  = (float2*)(ws + OFF_MT);
  float2* Sb  = (float2*)(ws + OFF_S);
  float2* Tt  = (float2*)(ws + OFF_X1);   // dead before X1 is written
  float*  X1  = (float*)(ws + OFF_X1);
  float2* Ab  = (float2*)(ws + OFF_A);
  float2* Bb  = (float2*)(ws + OFF_B);
  float2* A2L = (float2*)(ws + OFF_G);

  k_setup  <<<2048, 256, 0, stream>>>(p1, p2, txv, tyv, A1, A2T, A2L, E1, E2);
  k_T      <<<256, 256, 0, stream>>>(res, A1, Tt);
  k_stats_v<<<128, 256, 0, stream>>>(x, fc0w, fc0b, st1);
  // forward fft2: rows into Ab, columns into o-major alphaR (Bb)
  k_fft_v  <<<8192, 256, 0, stream>>>(x, fc0w, fc0b, st1, Ab);
  k_fft_colR<<<2048, 256, 0, stream>>>(Ab, Bb);                 // Bb = alphaR [o][bi][x]
  // pole-residue spectral sums
  k_S      <<<2048, 256, 0, stream>>>(Bb, A2T, Sb);
  k_Mt     <<<2048, 256, 0, stream>>>(Sb, A1, Mt);
  k_out2   <<<32, 256, 0, stream>>>(Mt, res, o2b);
  // fused out1 (G built on the fly, per (o, k-pair) block)
  k_out1g  <<<2048, 256, 0, stream>>>(Bb, Tt, A2L, Ab);         // Ab = out1 [img][o][x]
  // inverse fft2: rows then columns, real output
  k_fft_c  <<<8192, 256, 0, stream>>>(Ab, Bb, +1.f, 1.f);       // ifft over x
  k_ifft_col_real<<<2048, 256, 0, stream>>>(Bb, X1, 1.0f/65536.0f); // X1 [img][h][w]
  // transient part added into x1pre (U folded in)
  k_x2t    <<<4096, 256, 0, stream>>>(o2b, E1, E2, X1);
  // second instance norm + heads
  k_stats_p<<<128, 256, 0, stream>>>(X1, st2);
  k_final  <<<2048, 256, 0, stream>>>(x, X1, st2, fc0w, fc0b,
                                      w0w, w0b, fc1w, fc1b, fc2w, fc2b, out);
}